// Round 1
// 7813.068 us; speedup vs baseline: 1.2567x; 1.2567x over previous
//
#include <hip/hip_runtime.h>

typedef unsigned short u16;

#define TSEQ 2048
#define DMODEL 768
#define DFF 3072
#define NHEAD 12
#define HDIM 64
#define NLAYER 4
#define NVOCAB 32000
#define MROWS 4096   // B*T

typedef __attribute__((ext_vector_type(8))) __bf16 bf16x8;
typedef __attribute__((ext_vector_type(4))) float f32x4;
typedef __attribute__((ext_vector_type(8))) unsigned short us8;

__device__ __forceinline__ float u2f(u16 u) {
  return __uint_as_float(((unsigned int)u) << 16);
}
__device__ __forceinline__ u16 f2bu(float f) {
  unsigned int u = __float_as_uint(f);
  u += 0x7fffu + ((u >> 16) & 1u);   // round-to-nearest-even
  return (u16)(u >> 16);
}
// dtype probe: ln1_s is all-ones. bf16 -> first u16 = 0x3F80; f32 -> 0x0000 (LE low half).
__device__ __forceinline__ int probe_f32(const void* probe) {
  return ((const u16*)probe)[0] == 0 ? 1 : 0;
}
__device__ __forceinline__ float ldf(const void* p, size_t i, int f32) {
  return f32 ? ((const float*)p)[i] : u2f(((const u16*)p)[i]);
}
__device__ __forceinline__ void ld8(const void* p, size_t i, int f32, float* o) {
  if (f32) {
    const float* q = (const float*)p + i;
    float4 a = *(const float4*)q, b = *(const float4*)(q + 4);
    o[0]=a.x; o[1]=a.y; o[2]=a.z; o[3]=a.w; o[4]=b.x; o[5]=b.y; o[6]=b.z; o[7]=b.w;
  } else {
    const u16* q = (const u16*)p + i;
    ushort4 a = *(const ushort4*)q, b = *(const ushort4*)(q + 4);
    o[0]=u2f(a.x); o[1]=u2f(a.y); o[2]=u2f(a.z); o[3]=u2f(a.w);
    o[4]=u2f(b.x); o[5]=u2f(b.y); o[6]=u2f(b.z); o[7]=u2f(b.w);
  }
}
__device__ __forceinline__ us8 pack8(const float* f) {
  us8 r;
#pragma unroll
  for (int i = 0; i < 8; i++) r[i] = f2bu(f[i]);
  return r;
}

// ---------------- embedding ----------------
__global__ __launch_bounds__(256) void embed_kernel(const int* __restrict__ ids,
    const void* __restrict__ te, const void* __restrict__ pe, float* __restrict__ x,
    const void* probe) {
  int f32 = probe_f32(probe);
  int m = blockIdx.x;
  int t = m & (TSEQ - 1);
  int id = ids[m];
  float* xr = x + (size_t)m * DMODEL;
  for (int d = threadIdx.x; d < DMODEL; d += 256)
    xr[d] = ldf(te, (size_t)id * DMODEL + d, f32) + ldf(pe, (size_t)t * DMODEL + d, f32);
}

// ---------------- layernorm, one block per row; s/b at element offset soff ----------------
__global__ __launch_bounds__(256) void ln_kernel(const float* __restrict__ x,
    const void* __restrict__ s, const void* __restrict__ b, long soff,
    float* __restrict__ h, const void* probe) {
  int f32 = probe_f32(probe);
  int m = blockIdx.x;
  const float* xr = x + (size_t)m * DMODEL;
  float v[3];
  float lsum = 0.f, lsq = 0.f;
#pragma unroll
  for (int j = 0; j < 3; j++) {
    float t = xr[threadIdx.x + j * 256];
    v[j] = t; lsum += t; lsq += t * t;
  }
#pragma unroll
  for (int off = 32; off > 0; off >>= 1) {
    lsum += __shfl_down(lsum, off);
    lsq  += __shfl_down(lsq, off);
  }
  __shared__ float wsum[4], wsq[4];
  __shared__ float mu_s, rs_s;
  int wid = threadIdx.x >> 6, lane = threadIdx.x & 63;
  if (lane == 0) { wsum[wid] = lsum; wsq[wid] = lsq; }
  __syncthreads();
  if (threadIdx.x == 0) {
    float su = wsum[0] + wsum[1] + wsum[2] + wsum[3];
    float sq = wsq[0] + wsq[1] + wsq[2] + wsq[3];
    float mu = su * (1.f / DMODEL);
    float var = sq * (1.f / DMODEL) - mu * mu;
    mu_s = mu;
    rs_s = rsqrtf(var + 1e-5f);
  }
  __syncthreads();
  float mu = mu_s, rs = rs_s;
  float* hr = h + (size_t)m * DMODEL;
#pragma unroll
  for (int j = 0; j < 3; j++) {
    int d = threadIdx.x + j * 256;
    hr[d] = (v[j] - mu) * rs * ldf(s, soff + d, f32) + ldf(b, soff + d, f32);
  }
}

// ---------------- C[M,N] = A[M,K] @ W[K,N] + bias, fused epilogue ----------------
// W at element offset woff, bias at boff. mode 0: plain; 1: += resid; 2: silu.
// C may alias resid -> no __restrict__ on them.
__global__ __launch_bounds__(256) void gemm_nn(const float* __restrict__ A,
    const void* __restrict__ W, long woff, const void* __restrict__ bias, long boff,
    const float* resid, float* C, int N, int K, int mode, const void* probe) {
  int f32 = probe_f32(probe);
  __shared__ float As[16][132];
  __shared__ float Bs[16][132];
  const int tid = threadIdx.x;
  const int m0 = blockIdx.y << 7, n0 = blockIdx.x << 7;
  const int rbase = (tid >> 4) << 3;
  const int cbase = (tid & 15) << 3;
  const int ar = tid >> 1, ak = (tid & 1) << 3;
  const int wk = tid >> 4, wc = (tid & 15) << 3;
  float acc[8][8];
#pragma unroll
  for (int i = 0; i < 8; i++)
#pragma unroll
    for (int j = 0; j < 8; j++) acc[i][j] = 0.f;

  const float* Ab = A + (size_t)(m0 + ar) * K + ak;
  for (int k0 = 0; k0 < K; k0 += 16) {
    float4 a0 = *(const float4*)(Ab + k0);
    float4 a1 = *(const float4*)(Ab + k0 + 4);
    As[ak + 0][ar] = a0.x; As[ak + 1][ar] = a0.y; As[ak + 2][ar] = a0.z; As[ak + 3][ar] = a0.w;
    As[ak + 4][ar] = a1.x; As[ak + 5][ar] = a1.y; As[ak + 6][ar] = a1.z; As[ak + 7][ar] = a1.w;
    float w[8];
    ld8(W, (size_t)woff + (size_t)(k0 + wk) * N + n0 + wc, f32, w);
    *(float4*)&Bs[wk][wc]     = make_float4(w[0], w[1], w[2], w[3]);
    *(float4*)&Bs[wk][wc + 4] = make_float4(w[4], w[5], w[6], w[7]);
    __syncthreads();
#pragma unroll
    for (int kk = 0; kk < 16; kk++) {
      float a[8], b[8];
      *(float4*)&a[0] = *(const float4*)&As[kk][rbase];
      *(float4*)&a[4] = *(const float4*)&As[kk][rbase + 4];
      *(float4*)&b[0] = *(const float4*)&Bs[kk][cbase];
      *(float4*)&b[4] = *(const float4*)&Bs[kk][cbase + 4];
#pragma unroll
      for (int i = 0; i < 8; i++)
#pragma unroll
        for (int j = 0; j < 8; j++)
          acc[i][j] = fmaf(a[i], b[j], acc[i][j]);
    }
    __syncthreads();
  }
  float bv[8];
#pragma unroll
  for (int j = 0; j < 8; j++) bv[j] = ldf(bias, boff + n0 + cbase + j, f32);
#pragma unroll
  for (int i = 0; i < 8; i++) {
    size_t off = (size_t)(m0 + rbase + i) * N + n0 + cbase;
    float v[8];
#pragma unroll
    for (int j = 0; j < 8; j++) v[j] = acc[i][j] + bv[j];
    if (mode == 1) {
      float4 r0 = *(const float4*)(resid + off);
      float4 r1 = *(const float4*)(resid + off + 4);
      v[0] += r0.x; v[1] += r0.y; v[2] += r0.z; v[3] += r0.w;
      v[4] += r1.x; v[5] += r1.y; v[6] += r1.z; v[7] += r1.w;
    } else if (mode == 2) {
#pragma unroll
      for (int j = 0; j < 8; j++) v[j] = v[j] / (1.f + __expf(-v[j]));
    }
    *(float4*)(C + off)     = make_float4(v[0], v[1], v[2], v[3]);
    *(float4*)(C + off + 4) = make_float4(v[4], v[5], v[6], v[7]);
  }
}

// ---------------- logits head: C[M,N] = A[M,K] @ te[N,K]^T via bf16 MFMA ----------------
// B-fragment needs B^T[n][k] = te[n][k] -> te rows load coalesced, no transpose.
// A (f32 workspace) and te are rounded to bf16; accumulate f32 in MFMA.
// 128x128 tile, 4 waves of 64x64 (4x4 frags of 16x16), BK=32.
__global__ __launch_bounds__(256) void gemm_head_mfma(const float* __restrict__ A,
    const void* __restrict__ Wt, void* __restrict__ C, const void* probe) {
  const int f32 = probe_f32(probe);
  // [row][32 k + 8 pad] bf16: 80B rows -> lane bank stride 20, <=2-way (free).
  __shared__ __align__(16) u16 As[128][40];
  __shared__ __align__(16) u16 Bs[128][40];
  const int tid = threadIdx.x;
  const int m0 = blockIdx.y << 7, n0 = blockIdx.x << 7;
  const int lane = tid & 63;
  const int wr = ((tid >> 7) & 1) << 6;  // wave row origin within tile
  const int wc = ((tid >> 6) & 1) << 6;  // wave col origin within tile
  const int fm = lane & 15;              // A-row / B-col / D-col within fragment
  const int kl = lane >> 4;              // k-group (same mapping for A and B -> any
                                         // hw k-permutation cancels between operands)
  const int sr = tid >> 1, sc = (tid & 1) << 4;   // staging: row, 16-elem half

  f32x4 acc[4][4];
#pragma unroll
  for (int i = 0; i < 4; i++)
#pragma unroll
    for (int j = 0; j < 4; j++) acc[i][j] = (f32x4){0.f, 0.f, 0.f, 0.f};

  const float* Ab = A + (size_t)(m0 + sr) * DMODEL + sc;
  const size_t wbase = (size_t)(n0 + sr) * DMODEL + sc;

  for (int k0 = 0; k0 < DMODEL; k0 += 32) {
    float av[16];
    *(float4*)&av[0]  = *(const float4*)(Ab + k0);
    *(float4*)&av[4]  = *(const float4*)(Ab + k0 + 4);
    *(float4*)&av[8]  = *(const float4*)(Ab + k0 + 8);
    *(float4*)&av[12] = *(const float4*)(Ab + k0 + 12);
    float wv[16];
    ld8(Wt, wbase + k0, f32, wv);
    ld8(Wt, wbase + k0 + 8, f32, wv + 8);
    *(us8*)&As[sr][sc]     = pack8(av);
    *(us8*)&As[sr][sc + 8] = pack8(av + 8);
    *(us8*)&Bs[sr][sc]     = pack8(wv);
    *(us8*)&Bs[sr][sc + 8] = pack8(wv + 8);
    __syncthreads();
    bf16x8 af[4], bfr[4];
#pragma unroll
    for (int i = 0; i < 4; i++)
      af[i] = *reinterpret_cast<const bf16x8*>(&As[wr + i * 16 + fm][kl << 3]);
#pragma unroll
    for (int j = 0; j < 4; j++)
      bfr[j] = *reinterpret_cast<const bf16x8*>(&Bs[wc + j * 16 + fm][kl << 3]);
#pragma unroll
    for (int i = 0; i < 4; i++)
#pragma unroll
      for (int j = 0; j < 4; j++)
        acc[i][j] = __builtin_amdgcn_mfma_f32_16x16x32_bf16(af[i], bfr[j], acc[i][j], 0, 0, 0);
    __syncthreads();
  }

  // D mapping (m89-verified): col = lane&15, row = (lane>>4)*4 + reg
  const int rbase = m0 + wr + (kl << 2);
  const int cbase = n0 + wc + fm;
#pragma unroll
  for (int i = 0; i < 4; i++) {
#pragma unroll
    for (int j = 0; j < 4; j++) {
#pragma unroll
      for (int e = 0; e < 4; e++) {
        size_t off = (size_t)(rbase + i * 16 + e) * NVOCAB + cbase + j * 16;
        if (f32) ((float*)C)[off] = acc[i][j][e];
        else     ((u16*)C)[off]   = f2bu(acc[i][j][e]);
      }
    }
  }
}

// ---------------- flash-style causal attention (f32 workspace in/out) ----------------
__global__ __launch_bounds__(256) void attn_kernel(const float* __restrict__ qkv,
                                                   float* __restrict__ o) {
  const int qt = blockIdx.x, hh = blockIdx.y, bb = blockIdx.z;
  __shared__ float Qs[64][65];
  __shared__ float KsT[64][68];   // [d][key]
  __shared__ float Vs[64][68];    // [key][d]
  __shared__ float Ps[64][65];
  __shared__ float mrow[64], lrow[64], alpha_s[64], newm_s[64];
  const int tid = threadIdx.x;
  const int r = tid >> 2, cg = tid & 3;
  const int cb = cg << 4;
  float oacc[16];
#pragma unroll
  for (int j = 0; j < 16; j++) oacc[j] = 0.f;

  for (int idx = tid; idx < 4096; idx += 256) {
    int rr = idx >> 6, dd = idx & 63;
    Qs[rr][dd] = qkv[((size_t)(bb * TSEQ + qt * 64 + rr)) * 2304 + hh * 64 + dd] * 0.125f;
  }
  if (tid < 64) { mrow[tid] = -3e38f; lrow[tid] = 0.f; }
  __syncthreads();

  for (int kt = 0; kt <= qt; kt++) {
    for (int idx = tid; idx < 4096; idx += 256) {
      int rr = idx >> 6, dd = idx & 63;
      size_t base = ((size_t)(bb * TSEQ + kt * 64 + rr)) * 2304 + hh * 64 + dd;
      KsT[dd][rr] = qkv[base + 768];
      Vs[rr][dd]  = qkv[base + 1536];
    }
    __syncthreads();

    float sv[16];
#pragma unroll
    for (int j = 0; j < 16; j++) sv[j] = 0.f;
    for (int d = 0; d < 64; d++) {
      float qv = Qs[r][d];
      float kv[16];
      *(float4*)&kv[0]  = *(const float4*)&KsT[d][cb];
      *(float4*)&kv[4]  = *(const float4*)&KsT[d][cb + 4];
      *(float4*)&kv[8]  = *(const float4*)&KsT[d][cb + 8];
      *(float4*)&kv[12] = *(const float4*)&KsT[d][cb + 12];
#pragma unroll
      for (int j = 0; j < 16; j++) sv[j] = fmaf(qv, kv[j], sv[j]);
    }
    if (kt == qt) {
#pragma unroll
      for (int j = 0; j < 16; j++)
        if (cb + j > r) sv[j] = -3e38f;
    }
    float pmax = sv[0];
#pragma unroll
    for (int j = 1; j < 16; j++) pmax = fmaxf(pmax, sv[j]);
    pmax = fmaxf(pmax, __shfl_xor(pmax, 1, 4));
    pmax = fmaxf(pmax, __shfl_xor(pmax, 2, 4));
    if (cg == 0) {
      float nm = fmaxf(mrow[r], pmax);
      alpha_s[r] = __expf(mrow[r] - nm);
      newm_s[r] = nm;
      mrow[r] = nm;
    }
    __syncthreads();
    float nm = newm_s[r];
    float psum = 0.f;
#pragma unroll
    for (int j = 0; j < 16; j++) {
      float p = __expf(sv[j] - nm);
      Ps[r][cb + j] = p;
      psum += p;
    }
    psum += __shfl_xor(psum, 1, 4);
    psum += __shfl_xor(psum, 2, 4);
    if (cg == 0) lrow[r] = lrow[r] * alpha_s[r] + psum;
    __syncthreads();
    float al = alpha_s[r];
#pragma unroll
    for (int j = 0; j < 16; j++) oacc[j] *= al;
    for (int c = 0; c < 64; c++) {
      float p = Ps[r][c];
      float vv[16];
      *(float4*)&vv[0]  = *(const float4*)&Vs[c][cb];
      *(float4*)&vv[4]  = *(const float4*)&Vs[c][cb + 4];
      *(float4*)&vv[8]  = *(const float4*)&Vs[c][cb + 8];
      *(float4*)&vv[12] = *(const float4*)&Vs[c][cb + 12];
#pragma unroll
      for (int j = 0; j < 16; j++) oacc[j] = fmaf(p, vv[j], oacc[j]);
    }
    __syncthreads();
  }
  float linv = 1.f / lrow[r];
  size_t ob = ((size_t)(bb * TSEQ + qt * 64 + r)) * DMODEL + hh * 64 + cb;
  *(float4*)(o + ob)      = make_float4(oacc[0] * linv, oacc[1] * linv, oacc[2] * linv, oacc[3] * linv);
  *(float4*)(o + ob + 4)  = make_float4(oacc[4] * linv, oacc[5] * linv, oacc[6] * linv, oacc[7] * linv);
  *(float4*)(o + ob + 8)  = make_float4(oacc[8] * linv, oacc[9] * linv, oacc[10] * linv, oacc[11] * linv);
  *(float4*)(o + ob + 12) = make_float4(oacc[12] * linv, oacc[13] * linv, oacc[14] * linv, oacc[15] * linv);
}

extern "C" void kernel_launch(void* const* d_in, const int* in_sizes, int n_in,
                              void* d_out, int out_size, void* d_ws, size_t ws_size,
                              hipStream_t stream) {
  const int* ids = (const int*)d_in[0];
  const void* te    = d_in[1];
  const void* pe    = d_in[2];
  const void* ln1_s = d_in[3];
  const void* ln1_b = d_in[4];
  const void* qkv_w = d_in[5];
  const void* qkv_b = d_in[6];
  const void* out_w = d_in[7];
  const void* out_b = d_in[8];
  const void* ln2_s = d_in[9];
  const void* ln2_b = d_in[10];
  const void* up_w  = d_in[11];
  const void* up_b  = d_in[12];
  const void* dn_w  = d_in[13];
  const void* dn_b  = d_in[14];
  const void* lnf_s = d_in[15];
  const void* lnf_b = d_in[16];
  const void* probe = ln1_s;  // all-ones tensor -> dtype detection inside kernels

  float* x  = (float*)d_ws;                      // [4096][768]
  float* h  = x + (size_t)MROWS * DMODEL;        // [4096][768]
  float* ob = h + (size_t)MROWS * DMODEL;        // [4096][768] attn out
  float* qu = ob + (size_t)MROWS * DMODEL;       // union: qkv [4096][2304] / ffn [4096][3072]

  embed_kernel<<<MROWS, 256, 0, stream>>>(ids, te, pe, x, probe);
  for (int l = 0; l < NLAYER; l++) {
    long lD = (long)l * DMODEL;
    ln_kernel<<<MROWS, 256, 0, stream>>>(x, ln1_s, ln1_b, lD, h, probe);
    gemm_nn<<<dim3(18, 32), 256, 0, stream>>>(h, qkv_w, (long)l * DMODEL * 2304,
        qkv_b, (long)l * 2304, nullptr, qu, 2304, DMODEL, 0, probe);
    attn_kernel<<<dim3(32, 12, 2), 256, 0, stream>>>(qu, ob);
    gemm_nn<<<dim3(6, 32), 256, 0, stream>>>(ob, out_w, (long)l * DMODEL * DMODEL,
        out_b, lD, x, x, DMODEL, DMODEL, 1, probe);
    ln_kernel<<<MROWS, 256, 0, stream>>>(x, ln2_s, ln2_b, lD, h, probe);
    gemm_nn<<<dim3(24, 32), 256, 0, stream>>>(h, up_w, (long)l * DMODEL * DFF,
        up_b, (long)l * DFF, nullptr, qu, DFF, DMODEL, 2, probe);
    gemm_nn<<<dim3(6, 32), 256, 0, stream>>>(qu, dn_w, (long)l * DFF * DMODEL,
        dn_b, lD, x, x, DMODEL, DFF, 1, probe);
  }
  ln_kernel<<<MROWS, 256, 0, stream>>>(x, lnf_s, lnf_b, 0, h, probe);
  gemm_head_mfma<<<dim3(250, 32), 256, 0, stream>>>(h, te, d_out, probe);
}

// Round 2
// 4851.794 us; speedup vs baseline: 2.0237x; 1.6103x over previous
//
#include <hip/hip_runtime.h>

typedef unsigned short u16;

#define TSEQ 2048
#define DMODEL 768
#define DFF 3072
#define NHEAD 12
#define HDIM 64
#define NLAYER 4
#define NVOCAB 32000
#define MROWS 4096   // B*T

typedef __attribute__((ext_vector_type(8))) __bf16 bf16x8;
typedef __attribute__((ext_vector_type(4))) float f32x4;
typedef __attribute__((ext_vector_type(8))) unsigned short us8;

__device__ __forceinline__ float u2f(u16 u) {
  return __uint_as_float(((unsigned int)u) << 16);
}
__device__ __forceinline__ u16 f2bu(float f) {
  unsigned int u = __float_as_uint(f);
  u += 0x7fffu + ((u >> 16) & 1u);   // round-to-nearest-even
  return (u16)(u >> 16);
}
// dtype probe: ln1_s is all-ones. bf16 -> first u16 = 0x3F80; f32 -> 0x0000 (LE low half).
__device__ __forceinline__ int probe_f32(const void* probe) {
  return ((const u16*)probe)[0] == 0 ? 1 : 0;
}
__device__ __forceinline__ float ldf(const void* p, size_t i, int f32) {
  return f32 ? ((const float*)p)[i] : u2f(((const u16*)p)[i]);
}
__device__ __forceinline__ void ld8(const void* p, size_t i, int f32, float* o) {
  if (f32) {
    const float* q = (const float*)p + i;
    float4 a = *(const float4*)q, b = *(const float4*)(q + 4);
    o[0]=a.x; o[1]=a.y; o[2]=a.z; o[3]=a.w; o[4]=b.x; o[5]=b.y; o[6]=b.z; o[7]=b.w;
  } else {
    const u16* q = (const u16*)p + i;
    ushort4 a = *(const ushort4*)q, b = *(const ushort4*)(q + 4);
    o[0]=u2f(a.x); o[1]=u2f(a.y); o[2]=u2f(a.z); o[3]=u2f(a.w);
    o[4]=u2f(b.x); o[5]=u2f(b.y); o[6]=u2f(b.z); o[7]=u2f(b.w);
  }
}
__device__ __forceinline__ us8 pack8(const float* f) {
  us8 r;
#pragma unroll
  for (int i = 0; i < 8; i++) r[i] = f2bu(f[i]);
  return r;
}

// ---------------- embedding ----------------
__global__ __launch_bounds__(256) void embed_kernel(const int* __restrict__ ids,
    const void* __restrict__ te, const void* __restrict__ pe, float* __restrict__ x,
    const void* probe) {
  int f32 = probe_f32(probe);
  int m = blockIdx.x;
  int t = m & (TSEQ - 1);
  int id = ids[m];
  float* xr = x + (size_t)m * DMODEL;
  for (int d = threadIdx.x; d < DMODEL; d += 256)
    xr[d] = ldf(te, (size_t)id * DMODEL + d, f32) + ldf(pe, (size_t)t * DMODEL + d, f32);
}

// ---------------- layernorm, one block per row; s/b at element offset soff ----------------
__global__ __launch_bounds__(256) void ln_kernel(const float* __restrict__ x,
    const void* __restrict__ s, const void* __restrict__ b, long soff,
    float* __restrict__ h, const void* probe) {
  int f32 = probe_f32(probe);
  int m = blockIdx.x;
  const float* xr = x + (size_t)m * DMODEL;
  float v[3];
  float lsum = 0.f, lsq = 0.f;
#pragma unroll
  for (int j = 0; j < 3; j++) {
    float t = xr[threadIdx.x + j * 256];
    v[j] = t; lsum += t; lsq += t * t;
  }
#pragma unroll
  for (int off = 32; off > 0; off >>= 1) {
    lsum += __shfl_down(lsum, off);
    lsq  += __shfl_down(lsq, off);
  }
  __shared__ float wsum[4], wsq[4];
  __shared__ float mu_s, rs_s;
  int wid = threadIdx.x >> 6, lane = threadIdx.x & 63;
  if (lane == 0) { wsum[wid] = lsum; wsq[wid] = lsq; }
  __syncthreads();
  if (threadIdx.x == 0) {
    float su = wsum[0] + wsum[1] + wsum[2] + wsum[3];
    float sq = wsq[0] + wsq[1] + wsq[2] + wsq[3];
    float mu = su * (1.f / DMODEL);
    float var = sq * (1.f / DMODEL) - mu * mu;
    mu_s = mu;
    rs_s = rsqrtf(var + 1e-5f);
  }
  __syncthreads();
  float mu = mu_s, rs = rs_s;
  float* hr = h + (size_t)m * DMODEL;
#pragma unroll
  for (int j = 0; j < 3; j++) {
    int d = threadIdx.x + j * 256;
    hr[d] = (v[j] - mu) * rs * ldf(s, soff + d, f32) + ldf(b, soff + d, f32);
  }
}

// ---------------- weight transpose: Wt[n][k] (bf16) <- W[k][n] (f32/bf16) ----------------
// grid: (N/32, K/64, L); per-layer stride = K*N for both.
__global__ __launch_bounds__(256) void wtrans_kernel(const void* __restrict__ W,
    u16* __restrict__ Wt, int K, int N, const void* probe) {
  const int f32 = probe_f32(probe);
  __shared__ u16 t[64][33];
  const size_t ls = (size_t)K * N;
  const size_t off = (size_t)blockIdx.z * ls;
  const int k0 = blockIdx.y << 6, n0 = blockIdx.x << 5;
  const int tid = threadIdx.x;
  const int tn = tid & 31, tk8 = tid >> 5;
#pragma unroll
  for (int p = 0; p < 8; p++) {
    int k = (p << 3) + tk8;
    t[k][tn] = f2bu(ldf(W, off + (size_t)(k0 + k) * N + n0 + tn, f32));
  }
  __syncthreads();
  const int kp = (tid & 31) << 1, nb = tid >> 5;
#pragma unroll
  for (int p = 0; p < 4; p++) {
    int n = (p << 3) + nb;
    ushort2 v; v.x = t[kp][n]; v.y = t[kp + 1][n];
    *(ushort2*)&Wt[off + (size_t)(n0 + n) * K + k0 + kp] = v;
  }
}

// ---------------- fallback f32 GEMM (used only if workspace too small) ----------------
__global__ __launch_bounds__(256) void gemm_nn(const float* __restrict__ A,
    const void* __restrict__ W, long woff, const void* __restrict__ bias, long boff,
    const float* resid, float* C, int N, int K, int mode, const void* probe) {
  int f32 = probe_f32(probe);
  __shared__ float As[16][132];
  __shared__ float Bs[16][132];
  const int tid = threadIdx.x;
  const int m0 = blockIdx.y << 7, n0 = blockIdx.x << 7;
  const int rbase = (tid >> 4) << 3;
  const int cbase = (tid & 15) << 3;
  const int ar = tid >> 1, ak = (tid & 1) << 3;
  const int wk = tid >> 4, wc = (tid & 15) << 3;
  float acc[8][8];
#pragma unroll
  for (int i = 0; i < 8; i++)
#pragma unroll
    for (int j = 0; j < 8; j++) acc[i][j] = 0.f;

  const float* Ab = A + (size_t)(m0 + ar) * K + ak;
  for (int k0 = 0; k0 < K; k0 += 16) {
    float4 a0 = *(const float4*)(Ab + k0);
    float4 a1 = *(const float4*)(Ab + k0 + 4);
    As[ak + 0][ar] = a0.x; As[ak + 1][ar] = a0.y; As[ak + 2][ar] = a0.z; As[ak + 3][ar] = a0.w;
    As[ak + 4][ar] = a1.x; As[ak + 5][ar] = a1.y; As[ak + 6][ar] = a1.z; As[ak + 7][ar] = a1.w;
    float w[8];
    ld8(W, (size_t)woff + (size_t)(k0 + wk) * N + n0 + wc, f32, w);
    *(float4*)&Bs[wk][wc]     = make_float4(w[0], w[1], w[2], w[3]);
    *(float4*)&Bs[wk][wc + 4] = make_float4(w[4], w[5], w[6], w[7]);
    __syncthreads();
#pragma unroll
    for (int kk = 0; kk < 16; kk++) {
      float a[8], b[8];
      *(float4*)&a[0] = *(const float4*)&As[kk][rbase];
      *(float4*)&a[4] = *(const float4*)&As[kk][rbase + 4];
      *(float4*)&b[0] = *(const float4*)&Bs[kk][cbase];
      *(float4*)&b[4] = *(const float4*)&Bs[kk][cbase + 4];
#pragma unroll
      for (int i = 0; i < 8; i++)
#pragma unroll
        for (int j = 0; j < 8; j++)
          acc[i][j] = fmaf(a[i], b[j], acc[i][j]);
    }
    __syncthreads();
  }
  float bv[8];
#pragma unroll
  for (int j = 0; j < 8; j++) bv[j] = ldf(bias, boff + n0 + cbase + j, f32);
#pragma unroll
  for (int i = 0; i < 8; i++) {
    size_t off = (size_t)(m0 + rbase + i) * N + n0 + cbase;
    float v[8];
#pragma unroll
    for (int j = 0; j < 8; j++) v[j] = acc[i][j] + bv[j];
    if (mode == 1) {
      float4 r0 = *(const float4*)(resid + off);
      float4 r1 = *(const float4*)(resid + off + 4);
      v[0] += r0.x; v[1] += r0.y; v[2] += r0.z; v[3] += r0.w;
      v[4] += r1.x; v[5] += r1.y; v[6] += r1.z; v[7] += r1.w;
    } else if (mode == 2) {
#pragma unroll
      for (int j = 0; j < 8; j++) v[j] = v[j] / (1.f + __expf(-v[j]));
    }
    *(float4*)(C + off)     = make_float4(v[0], v[1], v[2], v[3]);
    *(float4*)(C + off + 4) = make_float4(v[4], v[5], v[6], v[7]);
  }
}

// ---------------- bf16 MFMA GEMM: C[M,N] = A[M,K] @ Wt[N,K]^T + bias ----------------
// A f32 (packed to bf16 in staging); Wt pre-transposed bf16. mode 0 plain / 1 +resid / 2 silu.
// 128x128 tile, 4 waves of 64x64 (4x4 frags of 16x16x32), BK=32.
__global__ __launch_bounds__(256) void gemm_mfma(const float* __restrict__ A,
    const u16* __restrict__ Wt, long woff, const void* __restrict__ bias, long boff,
    const float* resid, float* C, int N, int K, int mode, const void* probe) {
  const int f32 = probe_f32(probe);
  __shared__ __align__(16) u16 As[128][40];
  __shared__ __align__(16) u16 Bs[128][40];
  const int tid = threadIdx.x;
  const int m0 = blockIdx.y << 7, n0 = blockIdx.x << 7;
  const int lane = tid & 63;
  const int wr = ((tid >> 7) & 1) << 6;
  const int wc = ((tid >> 6) & 1) << 6;
  const int fm = lane & 15;
  const int kl = lane >> 4;
  const int sr = tid >> 1, sc = (tid & 1) << 4;

  f32x4 acc[4][4];
#pragma unroll
  for (int i = 0; i < 4; i++)
#pragma unroll
    for (int j = 0; j < 4; j++) acc[i][j] = (f32x4){0.f, 0.f, 0.f, 0.f};

  const float* Ab = A + (size_t)(m0 + sr) * K + sc;
  const u16* Wb = Wt + (size_t)woff + (size_t)(n0 + sr) * K + sc;

  for (int k0 = 0; k0 < K; k0 += 32) {
    float av[16];
    *(float4*)&av[0]  = *(const float4*)(Ab + k0);
    *(float4*)&av[4]  = *(const float4*)(Ab + k0 + 4);
    *(float4*)&av[8]  = *(const float4*)(Ab + k0 + 8);
    *(float4*)&av[12] = *(const float4*)(Ab + k0 + 12);
    us8 w0 = *(const us8*)(Wb + k0);
    us8 w1 = *(const us8*)(Wb + k0 + 8);
    *(us8*)&As[sr][sc]     = pack8(av);
    *(us8*)&As[sr][sc + 8] = pack8(av + 8);
    *(us8*)&Bs[sr][sc]     = w0;
    *(us8*)&Bs[sr][sc + 8] = w1;
    __syncthreads();
    bf16x8 af[4], bfr[4];
#pragma unroll
    for (int i = 0; i < 4; i++)
      af[i] = *reinterpret_cast<const bf16x8*>(&As[wr + i * 16 + fm][kl << 3]);
#pragma unroll
    for (int j = 0; j < 4; j++)
      bfr[j] = *reinterpret_cast<const bf16x8*>(&Bs[wc + j * 16 + fm][kl << 3]);
#pragma unroll
    for (int i = 0; i < 4; i++)
#pragma unroll
      for (int j = 0; j < 4; j++)
        acc[i][j] = __builtin_amdgcn_mfma_f32_16x16x32_bf16(af[i], bfr[j], acc[i][j], 0, 0, 0);
    __syncthreads();
  }

  // D mapping: col = lane&15, row = (lane>>4)*4 + reg
  const int rb = m0 + wr + (kl << 2);
  const int cb = n0 + wc + fm;
  float bv[4];
#pragma unroll
  for (int j = 0; j < 4; j++) bv[j] = ldf(bias, boff + cb + j * 16, f32);
#pragma unroll
  for (int i = 0; i < 4; i++) {
#pragma unroll
    for (int e = 0; e < 4; e++) {
      size_t roff = (size_t)(rb + i * 16 + e) * N;
#pragma unroll
      for (int j = 0; j < 4; j++) {
        float v = acc[i][j][e] + bv[j];
        if (mode == 1) v += resid[roff + cb + j * 16];
        else if (mode == 2) v = v / (1.f + __expf(-v));
        C[roff + cb + j * 16] = v;
      }
    }
  }
}

// ---------------- logits head: C[M,N] = A[M,K] @ te[N,K]^T via bf16 MFMA ----------------
__global__ __launch_bounds__(256) void gemm_head_mfma(const float* __restrict__ A,
    const void* __restrict__ Wt, void* __restrict__ C, const void* probe) {
  const int f32 = probe_f32(probe);
  __shared__ __align__(16) u16 As[128][40];
  __shared__ __align__(16) u16 Bs[128][40];
  const int tid = threadIdx.x;
  const int m0 = blockIdx.y << 7, n0 = blockIdx.x << 7;
  const int lane = tid & 63;
  const int wr = ((tid >> 7) & 1) << 6;
  const int wc = ((tid >> 6) & 1) << 6;
  const int fm = lane & 15;
  const int kl = lane >> 4;
  const int sr = tid >> 1, sc = (tid & 1) << 4;

  f32x4 acc[4][4];
#pragma unroll
  for (int i = 0; i < 4; i++)
#pragma unroll
    for (int j = 0; j < 4; j++) acc[i][j] = (f32x4){0.f, 0.f, 0.f, 0.f};

  const float* Ab = A + (size_t)(m0 + sr) * DMODEL + sc;
  const size_t wbase = (size_t)(n0 + sr) * DMODEL + sc;

  for (int k0 = 0; k0 < DMODEL; k0 += 32) {
    float av[16];
    *(float4*)&av[0]  = *(const float4*)(Ab + k0);
    *(float4*)&av[4]  = *(const float4*)(Ab + k0 + 4);
    *(float4*)&av[8]  = *(const float4*)(Ab + k0 + 8);
    *(float4*)&av[12] = *(const float4*)(Ab + k0 + 12);
    float wv[16];
    ld8(Wt, wbase + k0, f32, wv);
    ld8(Wt, wbase + k0 + 8, f32, wv + 8);
    *(us8*)&As[sr][sc]     = pack8(av);
    *(us8*)&As[sr][sc + 8] = pack8(av + 8);
    *(us8*)&Bs[sr][sc]     = pack8(wv);
    *(us8*)&Bs[sr][sc + 8] = pack8(wv + 8);
    __syncthreads();
    bf16x8 af[4], bfr[4];
#pragma unroll
    for (int i = 0; i < 4; i++)
      af[i] = *reinterpret_cast<const bf16x8*>(&As[wr + i * 16 + fm][kl << 3]);
#pragma unroll
    for (int j = 0; j < 4; j++)
      bfr[j] = *reinterpret_cast<const bf16x8*>(&Bs[wc + j * 16 + fm][kl << 3]);
#pragma unroll
    for (int i = 0; i < 4; i++)
#pragma unroll
      for (int j = 0; j < 4; j++)
        acc[i][j] = __builtin_amdgcn_mfma_f32_16x16x32_bf16(af[i], bfr[j], acc[i][j], 0, 0, 0);
    __syncthreads();
  }

  const int rbase = m0 + wr + (kl << 2);
  const int cbase = n0 + wc + fm;
#pragma unroll
  for (int i = 0; i < 4; i++) {
#pragma unroll
    for (int j = 0; j < 4; j++) {
#pragma unroll
      for (int e = 0; e < 4; e++) {
        size_t off = (size_t)(rbase + i * 16 + e) * NVOCAB + cbase + j * 16;
        if (f32) ((float*)C)[off] = acc[i][j][e];
        else     ((u16*)C)[off]   = f2bu(acc[i][j][e]);
      }
    }
  }
}

// ---------------- flash-style causal attention (f32 workspace in/out) ----------------
__global__ __launch_bounds__(256) void attn_kernel(const float* __restrict__ qkv,
                                                   float* __restrict__ o) {
  const int qt = blockIdx.x, hh = blockIdx.y, bb = blockIdx.z;
  __shared__ float Qs[64][65];
  __shared__ float KsT[64][68];   // [d][key]
  __shared__ float Vs[64][68];    // [key][d]
  __shared__ float Ps[64][65];
  __shared__ float mrow[64], lrow[64], alpha_s[64], newm_s[64];
  const int tid = threadIdx.x;
  const int r = tid >> 2, cg = tid & 3;
  const int cb = cg << 4;
  float oacc[16];
#pragma unroll
  for (int j = 0; j < 16; j++) oacc[j] = 0.f;

  for (int idx = tid; idx < 4096; idx += 256) {
    int rr = idx >> 6, dd = idx & 63;
    Qs[rr][dd] = qkv[((size_t)(bb * TSEQ + qt * 64 + rr)) * 2304 + hh * 64 + dd] * 0.125f;
  }
  if (tid < 64) { mrow[tid] = -3e38f; lrow[tid] = 0.f; }
  __syncthreads();

  for (int kt = 0; kt <= qt; kt++) {
    for (int idx = tid; idx < 4096; idx += 256) {
      int rr = idx >> 6, dd = idx & 63;
      size_t base = ((size_t)(bb * TSEQ + kt * 64 + rr)) * 2304 + hh * 64 + dd;
      KsT[dd][rr] = qkv[base + 768];
      Vs[rr][dd]  = qkv[base + 1536];
    }
    __syncthreads();

    float sv[16];
#pragma unroll
    for (int j = 0; j < 16; j++) sv[j] = 0.f;
    for (int d = 0; d < 64; d++) {
      float qv = Qs[r][d];
      float kv[16];
      *(float4*)&kv[0]  = *(const float4*)&KsT[d][cb];
      *(float4*)&kv[4]  = *(const float4*)&KsT[d][cb + 4];
      *(float4*)&kv[8]  = *(const float4*)&KsT[d][cb + 8];
      *(float4*)&kv[12] = *(const float4*)&KsT[d][cb + 12];
#pragma unroll
      for (int j = 0; j < 16; j++) sv[j] = fmaf(qv, kv[j], sv[j]);
    }
    if (kt == qt) {
#pragma unroll
      for (int j = 0; j < 16; j++)
        if (cb + j > r) sv[j] = -3e38f;
    }
    float pmax = sv[0];
#pragma unroll
    for (int j = 1; j < 16; j++) pmax = fmaxf(pmax, sv[j]);
    pmax = fmaxf(pmax, __shfl_xor(pmax, 1, 4));
    pmax = fmaxf(pmax, __shfl_xor(pmax, 2, 4));
    if (cg == 0) {
      float nm = fmaxf(mrow[r], pmax);
      alpha_s[r] = __expf(mrow[r] - nm);
      newm_s[r] = nm;
      mrow[r] = nm;
    }
    __syncthreads();
    float nm = newm_s[r];
    float psum = 0.f;
#pragma unroll
    for (int j = 0; j < 16; j++) {
      float p = __expf(sv[j] - nm);
      Ps[r][cb + j] = p;
      psum += p;
    }
    psum += __shfl_xor(psum, 1, 4);
    psum += __shfl_xor(psum, 2, 4);
    if (cg == 0) lrow[r] = lrow[r] * alpha_s[r] + psum;
    __syncthreads();
    float al = alpha_s[r];
#pragma unroll
    for (int j = 0; j < 16; j++) oacc[j] *= al;
    for (int c = 0; c < 64; c++) {
      float p = Ps[r][c];
      float vv[16];
      *(float4*)&vv[0]  = *(const float4*)&Vs[c][cb];
      *(float4*)&vv[4]  = *(const float4*)&Vs[c][cb + 4];
      *(float4*)&vv[8]  = *(const float4*)&Vs[c][cb + 8];
      *(float4*)&vv[12] = *(const float4*)&Vs[c][cb + 12];
#pragma unroll
      for (int j = 0; j < 16; j++) oacc[j] = fmaf(p, vv[j], oacc[j]);
    }
    __syncthreads();
  }
  float linv = 1.f / lrow[r];
  size_t ob = ((size_t)(bb * TSEQ + qt * 64 + r)) * DMODEL + hh * 64 + cb;
  *(float4*)(o + ob)      = make_float4(oacc[0] * linv, oacc[1] * linv, oacc[2] * linv, oacc[3] * linv);
  *(float4*)(o + ob + 4)  = make_float4(oacc[4] * linv, oacc[5] * linv, oacc[6] * linv, oacc[7] * linv);
  *(float4*)(o + ob + 8)  = make_float4(oacc[8] * linv, oacc[9] * linv, oacc[10] * linv, oacc[11] * linv);
  *(float4*)(o + ob + 12) = make_float4(oacc[12] * linv, oacc[13] * linv, oacc[14] * linv, oacc[15] * linv);
}

extern "C" void kernel_launch(void* const* d_in, const int* in_sizes, int n_in,
                              void* d_out, int out_size, void* d_ws, size_t ws_size,
                              hipStream_t stream) {
  const int* ids = (const int*)d_in[0];
  const void* te    = d_in[1];
  const void* pe    = d_in[2];
  const void* ln1_s = d_in[3];
  const void* ln1_b = d_in[4];
  const void* qkv_w = d_in[5];
  const void* qkv_b = d_in[6];
  const void* out_w = d_in[7];
  const void* out_b = d_in[8];
  const void* ln2_s = d_in[9];
  const void* ln2_b = d_in[10];
  const void* up_w  = d_in[11];
  const void* up_b  = d_in[12];
  const void* dn_w  = d_in[13];
  const void* dn_b  = d_in[14];
  const void* lnf_s = d_in[15];
  const void* lnf_b = d_in[16];
  const void* probe = ln1_s;  // all-ones tensor -> dtype detection inside kernels

  float* x  = (float*)d_ws;                      // [4096][768]
  float* h  = x + (size_t)MROWS * DMODEL;        // [4096][768]
  float* ob = h + (size_t)MROWS * DMODEL;        // [4096][768] attn out
  float* qu = ob + (size_t)MROWS * DMODEL;       // union: qkv [4096][2304] / ffn [4096][3072]

  // bf16 transposed weights after the f32 region
  const size_t base_f = (size_t)MROWS * DMODEL * 3 + (size_t)MROWS * DFF;
  u16* wt = (u16*)(x + base_f);
  const size_t qkv_t_sz = (size_t)2304 * 768;   // per layer, [N][K]
  const size_t out_t_sz = (size_t)768 * 768;
  const size_t up_t_sz  = (size_t)3072 * 768;
  const size_t dn_t_sz  = (size_t)768 * 3072;
  u16* qkv_t = wt;
  u16* out_t = qkv_t + NLAYER * qkv_t_sz;
  u16* up_t  = out_t + NLAYER * out_t_sz;
  u16* dn_t  = up_t  + NLAYER * up_t_sz;
  const size_t need = base_f * 4 +
      NLAYER * (qkv_t_sz + out_t_sz + up_t_sz + dn_t_sz) * 2;
  const int fast = ws_size >= need;

  embed_kernel<<<MROWS, 256, 0, stream>>>(ids, te, pe, x, probe);

  if (fast) {
    wtrans_kernel<<<dim3(2304/32, 768/64, NLAYER), 256, 0, stream>>>(qkv_w, qkv_t, 768, 2304, probe);
    wtrans_kernel<<<dim3(768/32,  768/64, NLAYER), 256, 0, stream>>>(out_w, out_t, 768, 768, probe);
    wtrans_kernel<<<dim3(3072/32, 768/64, NLAYER), 256, 0, stream>>>(up_w,  up_t,  768, 3072, probe);
    wtrans_kernel<<<dim3(768/32, 3072/64, NLAYER), 256, 0, stream>>>(dn_w,  dn_t,  3072, 768, probe);
  }

  for (int l = 0; l < NLAYER; l++) {
    long lD = (long)l * DMODEL;
    ln_kernel<<<MROWS, 256, 0, stream>>>(x, ln1_s, ln1_b, lD, h, probe);
    if (fast)
      gemm_mfma<<<dim3(18, 32), 256, 0, stream>>>(h, qkv_t, (long)l * qkv_t_sz,
          qkv_b, (long)l * 2304, nullptr, qu, 2304, DMODEL, 0, probe);
    else
      gemm_nn<<<dim3(18, 32), 256, 0, stream>>>(h, qkv_w, (long)l * DMODEL * 2304,
          qkv_b, (long)l * 2304, nullptr, qu, 2304, DMODEL, 0, probe);
    attn_kernel<<<dim3(32, 12, 2), 256, 0, stream>>>(qu, ob);
    if (fast)
      gemm_mfma<<<dim3(6, 32), 256, 0, stream>>>(ob, out_t, (long)l * out_t_sz,
          out_b, lD, x, x, DMODEL, DMODEL, 1, probe);
    else
      gemm_nn<<<dim3(6, 32), 256, 0, stream>>>(ob, out_w, (long)l * DMODEL * DMODEL,
          out_b, lD, x, x, DMODEL, DMODEL, 1, probe);
    ln_kernel<<<MROWS, 256, 0, stream>>>(x, ln2_s, ln2_b, lD, h, probe);
    if (fast)
      gemm_mfma<<<dim3(24, 32), 256, 0, stream>>>(h, up_t, (long)l * up_t_sz,
          up_b, (long)l * DFF, nullptr, qu, DFF, DMODEL, 2, probe);
    else
      gemm_nn<<<dim3(24, 32), 256, 0, stream>>>(h, up_w, (long)l * DMODEL * DFF,
          up_b, (long)l * DFF, nullptr, qu, DFF, DMODEL, 2, probe);
    if (fast)
      gemm_mfma<<<dim3(6, 32), 256, 0, stream>>>(qu, dn_t, (long)l * dn_t_sz,
          dn_b, lD, x, x, DMODEL, DFF, 1, probe);
    else
      gemm_nn<<<dim3(6, 32), 256, 0, stream>>>(qu, dn_w, (long)l * DFF * DMODEL,
          dn_b, lD, x, x, DMODEL, DFF, 1, probe);
  }
  ln_kernel<<<MROWS, 256, 0, stream>>>(x, lnf_s, lnf_b, 0, h, probe);
  gemm_head_mfma<<<dim3(250, 32), 256, 0, stream>>>(h, te, d_out, probe);
}

// Round 4
// 2669.268 us; speedup vs baseline: 3.6784x; 1.8176x over previous
//
#include <hip/hip_runtime.h>

typedef unsigned short u16;

#define TSEQ 2048
#define DMODEL 768
#define DFF 3072
#define NHEAD 12
#define HDIM 64
#define NLAYER 4
#define NVOCAB 32000
#define MROWS 4096   // B*T

typedef __attribute__((ext_vector_type(8))) __bf16 bf16x8;
typedef __attribute__((ext_vector_type(4))) float f32x4;
typedef __attribute__((ext_vector_type(8))) unsigned short us8;

__device__ __forceinline__ float u2f(u16 u) {
  return __uint_as_float(((unsigned int)u) << 16);
}
__device__ __forceinline__ u16 f2bu(float f) {
  unsigned int u = __float_as_uint(f);
  u += 0x7fffu + ((u >> 16) & 1u);   // round-to-nearest-even
  return (u16)(u >> 16);
}
// dtype probe: ln1_s is all-ones. bf16 -> first u16 = 0x3F80; f32 -> 0x0000 (LE low half).
__device__ __forceinline__ int probe_f32(const void* probe) {
  return ((const u16*)probe)[0] == 0 ? 1 : 0;
}
__device__ __forceinline__ float ldf(const void* p, size_t i, int f32) {
  return f32 ? ((const float*)p)[i] : u2f(((const u16*)p)[i]);
}
__device__ __forceinline__ void ld8(const void* p, size_t i, int f32, float* o) {
  if (f32) {
    const float* q = (const float*)p + i;
    float4 a = *(const float4*)q, b = *(const float4*)(q + 4);
    o[0]=a.x; o[1]=a.y; o[2]=a.z; o[3]=a.w; o[4]=b.x; o[5]=b.y; o[6]=b.z; o[7]=b.w;
  } else {
    const u16* q = (const u16*)p + i;
    ushort4 a = *(const ushort4*)q, b = *(const ushort4*)(q + 4);
    o[0]=u2f(a.x); o[1]=u2f(a.y); o[2]=u2f(a.z); o[3]=u2f(a.w);
    o[4]=u2f(b.x); o[5]=u2f(b.y); o[6]=u2f(b.z); o[7]=u2f(b.w);
  }
}
__device__ __forceinline__ us8 pack8(const float* f) {
  us8 r;
#pragma unroll
  for (int i = 0; i < 8; i++) r[i] = f2bu(f[i]);
  return r;
}

// ---------------- embedding ----------------
__global__ __launch_bounds__(256) void embed_kernel(const int* __restrict__ ids,
    const void* __restrict__ te, const void* __restrict__ pe, float* __restrict__ x,
    const void* probe) {
  int f32 = probe_f32(probe);
  int m = blockIdx.x;
  int t = m & (TSEQ - 1);
  int id = ids[m];
  float* xr = x + (size_t)m * DMODEL;
  for (int d = threadIdx.x; d < DMODEL; d += 256)
    xr[d] = ldf(te, (size_t)id * DMODEL + d, f32) + ldf(pe, (size_t)t * DMODEL + d, f32);
}

// ---------------- layernorm ----------------
__global__ __launch_bounds__(256) void ln_kernel(const float* __restrict__ x,
    const void* __restrict__ s, const void* __restrict__ b, long soff,
    float* __restrict__ h, const void* probe) {
  int f32 = probe_f32(probe);
  int m = blockIdx.x;
  const float* xr = x + (size_t)m * DMODEL;
  float v[3];
  float lsum = 0.f, lsq = 0.f;
#pragma unroll
  for (int j = 0; j < 3; j++) {
    float t = xr[threadIdx.x + j * 256];
    v[j] = t; lsum += t; lsq += t * t;
  }
#pragma unroll
  for (int off = 32; off > 0; off >>= 1) {
    lsum += __shfl_down(lsum, off);
    lsq  += __shfl_down(lsq, off);
  }
  __shared__ float wsum[4], wsq[4];
  __shared__ float mu_s, rs_s;
  int wid = threadIdx.x >> 6, lane = threadIdx.x & 63;
  if (lane == 0) { wsum[wid] = lsum; wsq[wid] = lsq; }
  __syncthreads();
  if (threadIdx.x == 0) {
    float su = wsum[0] + wsum[1] + wsum[2] + wsum[3];
    float sq = wsq[0] + wsq[1] + wsq[2] + wsq[3];
    float mu = su * (1.f / DMODEL);
    float var = sq * (1.f / DMODEL) - mu * mu;
    mu_s = mu;
    rs_s = rsqrtf(var + 1e-5f);
  }
  __syncthreads();
  float mu = mu_s, rs = rs_s;
  float* hr = h + (size_t)m * DMODEL;
#pragma unroll
  for (int j = 0; j < 3; j++) {
    int d = threadIdx.x + j * 256;
    hr[d] = (v[j] - mu) * rs * ldf(s, soff + d, f32) + ldf(b, soff + d, f32);
  }
}

// ---------------- weight transpose: Wt[n][k] (bf16) <- W[k][n] ----------------
__global__ __launch_bounds__(256) void wtrans_kernel(const void* __restrict__ W,
    u16* __restrict__ Wt, int K, int N, const void* probe) {
  const int f32 = probe_f32(probe);
  __shared__ u16 t[64][33];
  const size_t ls = (size_t)K * N;
  const size_t off = (size_t)blockIdx.z * ls;
  const int k0 = blockIdx.y << 6, n0 = blockIdx.x << 5;
  const int tid = threadIdx.x;
  const int tn = tid & 31, tk8 = tid >> 5;
#pragma unroll
  for (int p = 0; p < 8; p++) {
    int k = (p << 3) + tk8;
    t[k][tn] = f2bu(ldf(W, off + (size_t)(k0 + k) * N + n0 + tn, f32));
  }
  __syncthreads();
  const int kp = (tid & 31) << 1, nb = tid >> 5;
#pragma unroll
  for (int p = 0; p < 4; p++) {
    int n = (p << 3) + nb;
    ushort2 v; v.x = t[kp][n]; v.y = t[kp + 1][n];
    *(ushort2*)&Wt[off + (size_t)(n0 + n) * K + k0 + kp] = v;
  }
}

// ---------------- bf16 convert copy (te -> bf16 [N][K], no transpose) ----------------
__global__ __launch_bounds__(256) void cvt_bf16_kernel(const void* __restrict__ src,
    u16* __restrict__ dst, size_t n, const void* probe) {
  const int f32 = probe_f32(probe);
  size_t i = ((size_t)blockIdx.x * 256 + threadIdx.x) * 8;
  if (i >= n) return;
  float v[8];
  ld8(src, i, f32, v);
  *(us8*)&dst[i] = pack8(v);
}

// ---------------- fallback f32 GEMM (only if workspace too small) ----------------
__global__ __launch_bounds__(256) void gemm_nn(const float* __restrict__ A,
    const void* __restrict__ W, long woff, const void* __restrict__ bias, long boff,
    const float* resid, float* C, int N, int K, int mode, const void* probe) {
  int f32 = probe_f32(probe);
  __shared__ float As[16][132];
  __shared__ float Bs[16][132];
  const int tid = threadIdx.x;
  const int m0 = blockIdx.y << 7, n0 = blockIdx.x << 7;
  const int rbase = (tid >> 4) << 3;
  const int cbase = (tid & 15) << 3;
  const int ar = tid >> 1, ak = (tid & 1) << 3;
  const int wk = tid >> 4, wc = (tid & 15) << 3;
  float acc[8][8];
#pragma unroll
  for (int i = 0; i < 8; i++)
#pragma unroll
    for (int j = 0; j < 8; j++) acc[i][j] = 0.f;

  const float* Ab = A + (size_t)(m0 + ar) * K + ak;
  for (int k0 = 0; k0 < K; k0 += 16) {
    float4 a0 = *(const float4*)(Ab + k0);
    float4 a1 = *(const float4*)(Ab + k0 + 4);
    As[ak + 0][ar] = a0.x; As[ak + 1][ar] = a0.y; As[ak + 2][ar] = a0.z; As[ak + 3][ar] = a0.w;
    As[ak + 4][ar] = a1.x; As[ak + 5][ar] = a1.y; As[ak + 6][ar] = a1.z; As[ak + 7][ar] = a1.w;
    float w[8];
    ld8(W, (size_t)woff + (size_t)(k0 + wk) * N + n0 + wc, f32, w);
    *(float4*)&Bs[wk][wc]     = make_float4(w[0], w[1], w[2], w[3]);
    *(float4*)&Bs[wk][wc + 4] = make_float4(w[4], w[5], w[6], w[7]);
    __syncthreads();
#pragma unroll
    for (int kk = 0; kk < 16; kk++) {
      float a[8], b[8];
      *(float4*)&a[0] = *(const float4*)&As[kk][rbase];
      *(float4*)&a[4] = *(const float4*)&As[kk][rbase + 4];
      *(float4*)&b[0] = *(const float4*)&Bs[kk][cbase];
      *(float4*)&b[4] = *(const float4*)&Bs[kk][cbase + 4];
#pragma unroll
      for (int i = 0; i < 8; i++)
#pragma unroll
        for (int j = 0; j < 8; j++)
          acc[i][j] = fmaf(a[i], b[j], acc[i][j]);
    }
    __syncthreads();
  }
  float bv[8];
#pragma unroll
  for (int j = 0; j < 8; j++) bv[j] = ldf(bias, boff + n0 + cbase + j, f32);
#pragma unroll
  for (int i = 0; i < 8; i++) {
    size_t off = (size_t)(m0 + rbase + i) * N + n0 + cbase;
    float v[8];
#pragma unroll
    for (int j = 0; j < 8; j++) v[j] = acc[i][j] + bv[j];
    if (mode == 1) {
      float4 r0 = *(const float4*)(resid + off);
      float4 r1 = *(const float4*)(resid + off + 4);
      v[0] += r0.x; v[1] += r0.y; v[2] += r0.z; v[3] += r0.w;
      v[4] += r1.x; v[5] += r1.y; v[6] += r1.z; v[7] += r1.w;
    } else if (mode == 2) {
#pragma unroll
      for (int j = 0; j < 8; j++) v[j] = v[j] / (1.f + __expf(-v[j]));
    }
    *(float4*)(C + off)     = make_float4(v[0], v[1], v[2], v[3]);
    *(float4*)(C + off + 4) = make_float4(v[4], v[5], v[6], v[7]);
  }
}

// ---------------- bf16 MFMA GEMM: C[M,N] = A[M,K] @ Wt[N,K]^T + bias ----------------
__global__ __launch_bounds__(256) void gemm_mfma(const float* __restrict__ A,
    const u16* __restrict__ Wt, long woff, const void* __restrict__ bias, long boff,
    const float* resid, float* C, int N, int K, int mode, const void* probe) {
  const int f32 = probe_f32(probe);
  __shared__ __align__(16) u16 As[128][40];
  __shared__ __align__(16) u16 Bs[128][40];
  const int tid = threadIdx.x;
  const int m0 = blockIdx.y << 7, n0 = blockIdx.x << 7;
  const int lane = tid & 63;
  const int wr = ((tid >> 7) & 1) << 6;
  const int wc = ((tid >> 6) & 1) << 6;
  const int fm = lane & 15;
  const int kl = lane >> 4;
  const int sr = tid >> 1, sc = (tid & 1) << 4;

  f32x4 acc[4][4];
#pragma unroll
  for (int i = 0; i < 4; i++)
#pragma unroll
    for (int j = 0; j < 4; j++) acc[i][j] = (f32x4){0.f, 0.f, 0.f, 0.f};

  const float* Ab = A + (size_t)(m0 + sr) * K + sc;
  const u16* Wb = Wt + (size_t)woff + (size_t)(n0 + sr) * K + sc;

  for (int k0 = 0; k0 < K; k0 += 32) {
    float av[16];
    *(float4*)&av[0]  = *(const float4*)(Ab + k0);
    *(float4*)&av[4]  = *(const float4*)(Ab + k0 + 4);
    *(float4*)&av[8]  = *(const float4*)(Ab + k0 + 8);
    *(float4*)&av[12] = *(const float4*)(Ab + k0 + 12);
    us8 w0 = *(const us8*)(Wb + k0);
    us8 w1 = *(const us8*)(Wb + k0 + 8);
    *(us8*)&As[sr][sc]     = pack8(av);
    *(us8*)&As[sr][sc + 8] = pack8(av + 8);
    *(us8*)&Bs[sr][sc]     = w0;
    *(us8*)&Bs[sr][sc + 8] = w1;
    __syncthreads();
    bf16x8 af[4], bfr[4];
#pragma unroll
    for (int i = 0; i < 4; i++)
      af[i] = *reinterpret_cast<const bf16x8*>(&As[wr + i * 16 + fm][kl << 3]);
#pragma unroll
    for (int j = 0; j < 4; j++)
      bfr[j] = *reinterpret_cast<const bf16x8*>(&Bs[wc + j * 16 + fm][kl << 3]);
#pragma unroll
    for (int i = 0; i < 4; i++)
#pragma unroll
      for (int j = 0; j < 4; j++)
        acc[i][j] = __builtin_amdgcn_mfma_f32_16x16x32_bf16(af[i], bfr[j], acc[i][j], 0, 0, 0);
    __syncthreads();
  }

  const int rb = m0 + wr + (kl << 2);
  const int cb = n0 + wc + fm;
  float bv[4];
#pragma unroll
  for (int j = 0; j < 4; j++) bv[j] = ldf(bias, boff + cb + j * 16, f32);
#pragma unroll
  for (int i = 0; i < 4; i++) {
#pragma unroll
    for (int e = 0; e < 4; e++) {
      size_t roff = (size_t)(rb + i * 16 + e) * N;
#pragma unroll
      for (int j = 0; j < 4; j++) {
        float v = acc[i][j][e] + bv[j];
        if (mode == 1) v += resid[roff + cb + j * 16];
        else if (mode == 2) v = v / (1.f + __expf(-v));
        C[roff + cb + j * 16] = v;
      }
    }
  }
}

// ---------------- logits head: C[M,N] = A[M,K] @ te[N,K]^T via bf16 MFMA ----------------
// Grid (32 m, 250 n): m fast-varying -> 32 consecutive blocks share one te n-panel (L2/L3 reuse).
// Wtb (bf16 [N][K]) preferred; falls back to raw te + on-the-fly pack.
__global__ __launch_bounds__(256) void gemm_head_mfma(const float* __restrict__ A,
    const u16* __restrict__ Wtb, const void* __restrict__ Wt, void* __restrict__ C,
    const void* probe) {
  const int f32 = probe_f32(probe);
  __shared__ __align__(16) u16 As[128][40];
  __shared__ __align__(16) u16 Bs[128][40];
  const int tid = threadIdx.x;
  const int m0 = blockIdx.x << 7, n0 = blockIdx.y << 7;
  const int lane = tid & 63;
  const int wr = ((tid >> 7) & 1) << 6;
  const int wc = ((tid >> 6) & 1) << 6;
  const int fm = lane & 15;
  const int kl = lane >> 4;
  const int sr = tid >> 1, sc = (tid & 1) << 4;

  f32x4 acc[4][4];
#pragma unroll
  for (int i = 0; i < 4; i++)
#pragma unroll
    for (int j = 0; j < 4; j++) acc[i][j] = (f32x4){0.f, 0.f, 0.f, 0.f};

  const float* Ab = A + (size_t)(m0 + sr) * DMODEL + sc;
  const size_t wbase = (size_t)(n0 + sr) * DMODEL + sc;
  const u16* Wbb = Wtb ? Wtb + wbase : nullptr;

  for (int k0 = 0; k0 < DMODEL; k0 += 32) {
    float av[16];
    *(float4*)&av[0]  = *(const float4*)(Ab + k0);
    *(float4*)&av[4]  = *(const float4*)(Ab + k0 + 4);
    *(float4*)&av[8]  = *(const float4*)(Ab + k0 + 8);
    *(float4*)&av[12] = *(const float4*)(Ab + k0 + 12);
    *(us8*)&As[sr][sc]     = pack8(av);
    *(us8*)&As[sr][sc + 8] = pack8(av + 8);
    if (Wbb) {
      *(us8*)&Bs[sr][sc]     = *(const us8*)(Wbb + k0);
      *(us8*)&Bs[sr][sc + 8] = *(const us8*)(Wbb + k0 + 8);
    } else {
      float wv[16];
      ld8(Wt, wbase + k0, f32, wv);
      ld8(Wt, wbase + k0 + 8, f32, wv + 8);
      *(us8*)&Bs[sr][sc]     = pack8(wv);
      *(us8*)&Bs[sr][sc + 8] = pack8(wv + 8);
    }
    __syncthreads();
    bf16x8 af[4], bfr[4];
#pragma unroll
    for (int i = 0; i < 4; i++)
      af[i] = *reinterpret_cast<const bf16x8*>(&As[wr + i * 16 + fm][kl << 3]);
#pragma unroll
    for (int j = 0; j < 4; j++)
      bfr[j] = *reinterpret_cast<const bf16x8*>(&Bs[wc + j * 16 + fm][kl << 3]);
#pragma unroll
    for (int i = 0; i < 4; i++)
#pragma unroll
      for (int j = 0; j < 4; j++)
        acc[i][j] = __builtin_amdgcn_mfma_f32_16x16x32_bf16(af[i], bfr[j], acc[i][j], 0, 0, 0);
    __syncthreads();
  }

  const int rbase = m0 + wr + (kl << 2);
  const int cbase = n0 + wc + fm;
#pragma unroll
  for (int i = 0; i < 4; i++) {
#pragma unroll
    for (int j = 0; j < 4; j++) {
#pragma unroll
      for (int e = 0; e < 4; e++) {
        size_t off = (size_t)(rbase + i * 16 + e) * NVOCAB + cbase + j * 16;
        if (f32) ((float*)C)[off] = acc[i][j][e];
        else     ((u16*)C)[off]   = f2bu(acc[i][j][e]);
      }
    }
  }
}

// ---------------- MFMA flash attention ----------------
// Block = 4 waves; wave w owns q rows [qt*64 + w*16, +16). Q in registers (A-frags, bf16,
// pre-scaled). Per kt-tile: K rows -> LDS (B-frag for QK^T), V -> LDS transposed (B-frag
// for PV), softmax in-register (lane holds S rows kl*4+e, cols fm+16j; row-reduce via
// shfl_xor over fm bits), P -> LDS bf16 re-read as A-frag (same wave only, no barrier).
__global__ __launch_bounds__(256) void attn_mfma(const float* __restrict__ qkv,
                                                 float* __restrict__ o) {
  const int qt = blockIdx.x, hh = blockIdx.y, bb = blockIdx.z;
  __shared__ __align__(16) u16 Ks[64][72];   // K[key][d]
  __shared__ __align__(16) u16 Vt[64][72];   // V^T[d][key]
  __shared__ __align__(16) u16 Ps[64][72];   // P[q][key], per-wave 16-row slabs
  const int tid = threadIdx.x;
  const int w = tid >> 6, lane = tid & 63;
  const int fm = lane & 15, kl = lane >> 4;

  // Q fragments: lane holds Q[w*16+fm][c*32 + kl*8 + e] * 0.125, c=0,1
  bf16x8 aq[2];
  {
    const float* qrow = qkv + ((size_t)(bb * TSEQ + qt * 64 + w * 16 + fm)) * 2304 + hh * 64;
#pragma unroll
    for (int c = 0; c < 2; c++) {
      float4 q0 = *(const float4*)(qrow + c * 32 + kl * 8);
      float4 q1 = *(const float4*)(qrow + c * 32 + kl * 8 + 4);
      float qv[8] = {q0.x * 0.125f, q0.y * 0.125f, q0.z * 0.125f, q0.w * 0.125f,
                     q1.x * 0.125f, q1.y * 0.125f, q1.z * 0.125f, q1.w * 0.125f};
      us8 u = pack8(qv);
      aq[c] = *(bf16x8*)&u;
    }
  }

  float m_r[4], l_r[4];
#pragma unroll
  for (int e = 0; e < 4; e++) { m_r[e] = -3e38f; l_r[e] = 0.f; }
  f32x4 oacc[4];
#pragma unroll
  for (int j = 0; j < 4; j++) oacc[j] = (f32x4){0.f, 0.f, 0.f, 0.f};

  for (int kt = 0; kt <= qt; kt++) {
    const size_t kbase = ((size_t)(bb * TSEQ + kt * 64)) * 2304 + hh * 64;
    // stage K (row-major, coalesced) and V (transposed; 64 lanes of a wave write one
    // d-column at consecutive keys -> 128B span -> conflict-free).
    // idx in [0,512): K: row=idx>>3, col-chunk=(idx&7)*8. V: key=idx&63, d-chunk=(idx>>6)*8.
#pragma unroll
    for (int it = 0; it < 2; it++) {
      int idx = tid + it * 256;
      int row = idx >> 3, cb = (idx & 7) << 3;
      const float* kr = qkv + kbase + (size_t)row * 2304 + 768 + cb;
      float4 k0 = *(const float4*)kr, k1 = *(const float4*)(kr + 4);
      float kv[8] = {k0.x, k0.y, k0.z, k0.w, k1.x, k1.y, k1.z, k1.w};
      *(us8*)&Ks[row][cb] = pack8(kv);
      int row2 = idx & 63, cb2 = (idx >> 6) << 3;   // FIX: idx already includes it*256
      const float* vr = qkv + kbase + (size_t)row2 * 2304 + 1536 + cb2;
      float4 v0 = *(const float4*)vr, v1 = *(const float4*)(vr + 4);
      float vv[8] = {v0.x, v0.y, v0.z, v0.w, v1.x, v1.y, v1.z, v1.w};
#pragma unroll
      for (int e = 0; e < 8; e++) Vt[cb2 + e][row2] = f2bu(vv[e]);
    }
    __syncthreads();

    // S = Q K^T  (D rows kl*4+e, cols fm+16j)
    f32x4 sacc[4];
#pragma unroll
    for (int j = 0; j < 4; j++) sacc[j] = (f32x4){0.f, 0.f, 0.f, 0.f};
#pragma unroll
    for (int ck = 0; ck < 2; ck++) {
      bf16x8 kb[4];
#pragma unroll
      for (int j = 0; j < 4; j++)
        kb[j] = *reinterpret_cast<const bf16x8*>(&Ks[j * 16 + fm][ck * 32 + (kl << 3)]);
#pragma unroll
      for (int j = 0; j < 4; j++)
        sacc[j] = __builtin_amdgcn_mfma_f32_16x16x32_bf16(aq[ck], kb[j], sacc[j], 0, 0, 0);
    }
    if (kt == qt) {
      const int qrow0 = w * 16 + (kl << 2);
#pragma unroll
      for (int j = 0; j < 4; j++)
#pragma unroll
        for (int e = 0; e < 4; e++)
          if (j * 16 + fm > qrow0 + e) sacc[j][e] = -3e38f;
    }
    // online softmax
    float pmax[4];
#pragma unroll
    for (int e = 0; e < 4; e++) {
      pmax[e] = fmaxf(fmaxf(sacc[0][e], sacc[1][e]), fmaxf(sacc[2][e], sacc[3][e]));
    }
#pragma unroll
    for (int msk = 1; msk < 16; msk <<= 1)
#pragma unroll
      for (int e = 0; e < 4; e++) pmax[e] = fmaxf(pmax[e], __shfl_xor(pmax[e], msk));
    float al[4];
#pragma unroll
    for (int e = 0; e < 4; e++) {
      float nm = fmaxf(m_r[e], pmax[e]);
      al[e] = __expf(m_r[e] - nm);
      m_r[e] = nm;
    }
    float psum[4] = {0.f, 0.f, 0.f, 0.f};
#pragma unroll
    for (int j = 0; j < 4; j++)
#pragma unroll
      for (int e = 0; e < 4; e++) {
        float p = __expf(sacc[j][e] - m_r[e]);
        sacc[j][e] = p;
        psum[e] += p;
      }
    // stage P (bf16) for PV A-frag; same-wave rows only -> no barrier needed
#pragma unroll
    for (int j = 0; j < 4; j++)
#pragma unroll
      for (int e = 0; e < 4; e++)
        Ps[w * 16 + (kl << 2) + e][j * 16 + fm] = f2bu(sacc[j][e]);
#pragma unroll
    for (int msk = 1; msk < 16; msk <<= 1)
#pragma unroll
      for (int e = 0; e < 4; e++) psum[e] += __shfl_xor(psum[e], msk);
#pragma unroll
    for (int e = 0; e < 4; e++) l_r[e] = l_r[e] * al[e] + psum[e];
#pragma unroll
    for (int j = 0; j < 4; j++)
#pragma unroll
      for (int e = 0; e < 4; e++) oacc[j][e] *= al[e];
    // O += P V
#pragma unroll
    for (int ck = 0; ck < 2; ck++) {
      bf16x8 pa = *reinterpret_cast<const bf16x8*>(&Ps[w * 16 + fm][ck * 32 + (kl << 3)]);
      bf16x8 vb[4];
#pragma unroll
      for (int j = 0; j < 4; j++)
        vb[j] = *reinterpret_cast<const bf16x8*>(&Vt[j * 16 + fm][ck * 32 + (kl << 3)]);
#pragma unroll
      for (int j = 0; j < 4; j++)
        oacc[j] = __builtin_amdgcn_mfma_f32_16x16x32_bf16(pa, vb[j], oacc[j], 0, 0, 0);
    }
    __syncthreads();
  }

  float linv[4];
#pragma unroll
  for (int e = 0; e < 4; e++) linv[e] = 1.f / l_r[e];
#pragma unroll
  for (int e = 0; e < 4; e++) {
    size_t ob = ((size_t)(bb * TSEQ + qt * 64 + w * 16 + (kl << 2) + e)) * DMODEL + hh * 64 + fm;
#pragma unroll
    for (int j = 0; j < 4; j++) o[ob + j * 16] = oacc[j][e] * linv[e];
  }
}

extern "C" void kernel_launch(void* const* d_in, const int* in_sizes, int n_in,
                              void* d_out, int out_size, void* d_ws, size_t ws_size,
                              hipStream_t stream) {
  const int* ids = (const int*)d_in[0];
  const void* te    = d_in[1];
  const void* pe    = d_in[2];
  const void* ln1_s = d_in[3];
  const void* ln1_b = d_in[4];
  const void* qkv_w = d_in[5];
  const void* qkv_b = d_in[6];
  const void* out_w = d_in[7];
  const void* out_b = d_in[8];
  const void* ln2_s = d_in[9];
  const void* ln2_b = d_in[10];
  const void* up_w  = d_in[11];
  const void* up_b  = d_in[12];
  const void* dn_w  = d_in[13];
  const void* dn_b  = d_in[14];
  const void* lnf_s = d_in[15];
  const void* lnf_b = d_in[16];
  const void* probe = ln1_s;

  float* x  = (float*)d_ws;                      // [4096][768]
  float* h  = x + (size_t)MROWS * DMODEL;        // [4096][768]
  float* ob = h + (size_t)MROWS * DMODEL;        // [4096][768] attn out
  float* qu = ob + (size_t)MROWS * DMODEL;       // union: qkv [4096][2304] / ffn [4096][3072]

  const size_t base_f = (size_t)MROWS * DMODEL * 3 + (size_t)MROWS * DFF;
  u16* wt = (u16*)(x + base_f);
  const size_t qkv_t_sz = (size_t)2304 * 768;
  const size_t out_t_sz = (size_t)768 * 768;
  const size_t up_t_sz  = (size_t)3072 * 768;
  const size_t dn_t_sz  = (size_t)768 * 3072;
  u16* qkv_t = wt;
  u16* out_t = qkv_t + NLAYER * qkv_t_sz;
  u16* up_t  = out_t + NLAYER * out_t_sz;
  u16* dn_t  = up_t  + NLAYER * up_t_sz;
  const size_t w_sz = NLAYER * (qkv_t_sz + out_t_sz + up_t_sz + dn_t_sz);
  u16* tebf  = dn_t + NLAYER * dn_t_sz;
  const size_t te_sz = (size_t)NVOCAB * DMODEL;
  const size_t need_basic = base_f * 4 + w_sz * 2;
  const size_t need_te    = need_basic + te_sz * 2;
  const int fast = ws_size >= need_basic;
  // head B source: always materialize bf16 te copy when workspace allows (probe-driven
  // convert handles both input dtypes; identity round-trip if already bf16).
  const u16* head_wt = nullptr;
  int cvt_te = 0;
  if (ws_size >= need_te) { head_wt = tebf; cvt_te = 1; }

  embed_kernel<<<MROWS, 256, 0, stream>>>(ids, te, pe, x, probe);

  if (fast) {
    wtrans_kernel<<<dim3(2304/32, 768/64, NLAYER), 256, 0, stream>>>(qkv_w, qkv_t, 768, 2304, probe);
    wtrans_kernel<<<dim3(768/32,  768/64, NLAYER), 256, 0, stream>>>(out_w, out_t, 768, 768, probe);
    wtrans_kernel<<<dim3(3072/32, 768/64, NLAYER), 256, 0, stream>>>(up_w,  up_t,  768, 3072, probe);
    wtrans_kernel<<<dim3(768/32, 3072/64, NLAYER), 256, 0, stream>>>(dn_w,  dn_t,  3072, 768, probe);
  }
  if (cvt_te)
    cvt_bf16_kernel<<<(int)((te_sz / 8 + 255) / 256), 256, 0, stream>>>(te, tebf, te_sz, probe);

  for (int l = 0; l < NLAYER; l++) {
    long lD = (long)l * DMODEL;
    ln_kernel<<<MROWS, 256, 0, stream>>>(x, ln1_s, ln1_b, lD, h, probe);
    if (fast)
      gemm_mfma<<<dim3(18, 32), 256, 0, stream>>>(h, qkv_t, (long)l * qkv_t_sz,
          qkv_b, (long)l * 2304, nullptr, qu, 2304, DMODEL, 0, probe);
    else
      gemm_nn<<<dim3(18, 32), 256, 0, stream>>>(h, qkv_w, (long)l * DMODEL * 2304,
          qkv_b, (long)l * 2304, nullptr, qu, 2304, DMODEL, 0, probe);
    attn_mfma<<<dim3(32, 12, 2), 256, 0, stream>>>(qu, ob);
    if (fast)
      gemm_mfma<<<dim3(6, 32), 256, 0, stream>>>(ob, out_t, (long)l * out_t_sz,
          out_b, lD, x, x, DMODEL, DMODEL, 1, probe);
    else
      gemm_nn<<<dim3(6, 32), 256, 0, stream>>>(ob, out_w, (long)l * DMODEL * DMODEL,
          out_b, lD, x, x, DMODEL, DMODEL, 1, probe);
    ln_kernel<<<MROWS, 256, 0, stream>>>(x, ln2_s, ln2_b, lD, h, probe);
    if (fast)
      gemm_mfma<<<dim3(24, 32), 256, 0, stream>>>(h, up_t, (long)l * up_t_sz,
          up_b, (long)l * DFF, nullptr, qu, DFF, DMODEL, 2, probe);
    else
      gemm_nn<<<dim3(24, 32), 256, 0, stream>>>(h, up_w, (long)l * DMODEL * DFF,
          up_b, (long)l * DFF, nullptr, qu, DFF, DMODEL, 2, probe);
    if (fast)
      gemm_mfma<<<dim3(6, 32), 256, 0, stream>>>(qu, dn_t, (long)l * dn_t_sz,
          dn_b, lD, x, x, DMODEL, DFF, 1, probe);
    else
      gemm_nn<<<dim3(6, 32), 256, 0, stream>>>(qu, dn_w, (long)l * DFF * DMODEL,
          dn_b, lD, x, x, DMODEL, DFF, 1, probe);
  }
  ln_kernel<<<MROWS, 256, 0, stream>>>(x, lnf_s, lnf_b, 0, h, probe);
  gemm_head_mfma<<<dim3(32, 250), 256, 0, stream>>>(h, head_wt, te, d_out, probe);
}

// Round 5
// 2360.106 us; speedup vs baseline: 4.1603x; 1.1310x over previous
//
#include <hip/hip_runtime.h>

typedef unsigned short u16;

#define TSEQ 2048
#define DMODEL 768
#define DFF 3072
#define NHEAD 12
#define HDIM 64
#define NLAYER 4
#define NVOCAB 32000
#define MROWS 4096   // B*T

typedef __attribute__((ext_vector_type(8))) __bf16 bf16x8;
typedef __attribute__((ext_vector_type(4))) float f32x4;
typedef __attribute__((ext_vector_type(8))) unsigned short us8;

__device__ __forceinline__ float u2f(u16 u) {
  return __uint_as_float(((unsigned int)u) << 16);
}
__device__ __forceinline__ u16 f2bu(float f) {
  unsigned int u = __float_as_uint(f);
  u += 0x7fffu + ((u >> 16) & 1u);   // round-to-nearest-even
  return (u16)(u >> 16);
}
// dtype probe: ln1_s is all-ones. bf16 -> first u16 = 0x3F80; f32 -> 0x0000 (LE low half).
__device__ __forceinline__ int probe_f32(const void* probe) {
  return ((const u16*)probe)[0] == 0 ? 1 : 0;
}
__device__ __forceinline__ float ldf(const void* p, size_t i, int f32) {
  return f32 ? ((const float*)p)[i] : u2f(((const u16*)p)[i]);
}
__device__ __forceinline__ void ld8(const void* p, size_t i, int f32, float* o) {
  if (f32) {
    const float* q = (const float*)p + i;
    float4 a = *(const float4*)q, b = *(const float4*)(q + 4);
    o[0]=a.x; o[1]=a.y; o[2]=a.z; o[3]=a.w; o[4]=b.x; o[5]=b.y; o[6]=b.z; o[7]=b.w;
  } else {
    const u16* q = (const u16*)p + i;
    ushort4 a = *(const ushort4*)q, b = *(const ushort4*)(q + 4);
    o[0]=u2f(a.x); o[1]=u2f(a.y); o[2]=u2f(a.z); o[3]=u2f(a.w);
    o[4]=u2f(b.x); o[5]=u2f(b.y); o[6]=u2f(b.z); o[7]=u2f(b.w);
  }
}
__device__ __forceinline__ us8 pack8(const float* f) {
  us8 r;
#pragma unroll
  for (int i = 0; i < 8; i++) r[i] = f2bu(f[i]);
  return r;
}

// ---------------- embedding (f32 residual stream) ----------------
__global__ __launch_bounds__(256) void embed_kernel(const int* __restrict__ ids,
    const void* __restrict__ te, const void* __restrict__ pe, float* __restrict__ x,
    const void* probe) {
  int f32 = probe_f32(probe);
  int m = blockIdx.x;
  int t = m & (TSEQ - 1);
  int id = ids[m];
  float* xr = x + (size_t)m * DMODEL;
  for (int d = threadIdx.x; d < DMODEL; d += 256)
    xr[d] = ldf(te, (size_t)id * DMODEL + d, f32) + ldf(pe, (size_t)t * DMODEL + d, f32);
}

// ---------------- layernorm: f32 in, bf16 out ----------------
__global__ __launch_bounds__(256) void ln_kernel(const float* __restrict__ x,
    const void* __restrict__ s, const void* __restrict__ b, long soff,
    u16* __restrict__ h, const void* probe) {
  int f32 = probe_f32(probe);
  int m = blockIdx.x;
  const float* xr = x + (size_t)m * DMODEL;
  float v[3];
  float lsum = 0.f, lsq = 0.f;
#pragma unroll
  for (int j = 0; j < 3; j++) {
    float t = xr[threadIdx.x + j * 256];
    v[j] = t; lsum += t; lsq += t * t;
  }
#pragma unroll
  for (int off = 32; off > 0; off >>= 1) {
    lsum += __shfl_down(lsum, off);
    lsq  += __shfl_down(lsq, off);
  }
  __shared__ float wsum[4], wsq[4];
  __shared__ float mu_s, rs_s;
  int wid = threadIdx.x >> 6, lane = threadIdx.x & 63;
  if (lane == 0) { wsum[wid] = lsum; wsq[wid] = lsq; }
  __syncthreads();
  if (threadIdx.x == 0) {
    float su = wsum[0] + wsum[1] + wsum[2] + wsum[3];
    float sq = wsq[0] + wsq[1] + wsq[2] + wsq[3];
    float mu = su * (1.f / DMODEL);
    float var = sq * (1.f / DMODEL) - mu * mu;
    mu_s = mu;
    rs_s = rsqrtf(var + 1e-5f);
  }
  __syncthreads();
  float mu = mu_s, rs = rs_s;
  u16* hr = h + (size_t)m * DMODEL;
#pragma unroll
  for (int j = 0; j < 3; j++) {
    int d = threadIdx.x + j * 256;
    hr[d] = f2bu((v[j] - mu) * rs * ldf(s, soff + d, f32) + ldf(b, soff + d, f32));
  }
}

// ---------------- weight transpose: Wt[n][k] (bf16) <- W[k][n] ----------------
__global__ __launch_bounds__(256) void wtrans_kernel(const void* __restrict__ W,
    u16* __restrict__ Wt, int K, int N, const void* probe) {
  const int f32 = probe_f32(probe);
  __shared__ u16 t[64][33];
  const size_t ls = (size_t)K * N;
  const size_t off = (size_t)blockIdx.z * ls;
  const int k0 = blockIdx.y << 6, n0 = blockIdx.x << 5;
  const int tid = threadIdx.x;
  const int tn = tid & 31, tk8 = tid >> 5;
#pragma unroll
  for (int p = 0; p < 8; p++) {
    int k = (p << 3) + tk8;
    t[k][tn] = f2bu(ldf(W, off + (size_t)(k0 + k) * N + n0 + tn, f32));
  }
  __syncthreads();
  const int kp = (tid & 31) << 1, nb = tid >> 5;
#pragma unroll
  for (int p = 0; p < 4; p++) {
    int n = (p << 3) + nb;
    ushort2 v; v.x = t[kp][n]; v.y = t[kp + 1][n];
    *(ushort2*)&Wt[off + (size_t)(n0 + n) * K + k0 + kp] = v;
  }
}

// ---------------- bf16 convert copy (te -> bf16 [N][K], no transpose) ----------------
__global__ __launch_bounds__(256) void cvt_bf16_kernel(const void* __restrict__ src,
    u16* __restrict__ dst, size_t n, const void* probe) {
  const int f32 = probe_f32(probe);
  size_t i = ((size_t)blockIdx.x * 256 + threadIdx.x) * 8;
  if (i >= n) return;
  float v[8];
  ld8(src, i, f32, v);
  *(us8*)&dst[i] = pack8(v);
}

// ---------------- bf16 MFMA GEMM: C[M,N] = A[M,K] @ Wt[N,K]^T + bias ----------------
// A bf16, Wt bf16 [N][K]. mode 0: C bf16 plain; 1: C f32 += resid; 2: C bf16 silu.
// 128x128 tile, 4 waves of 64x64 (4x4 frags of 16x16x32), BK=32. Staging = pure us8 copy.
__global__ __launch_bounds__(256) void gemm_mfma(const u16* __restrict__ A,
    const u16* __restrict__ Wt, long woff, const void* __restrict__ bias, long boff,
    const float* resid, void* C, int N, int K, int mode, const void* probe) {
  const int f32 = probe_f32(probe);
  __shared__ __align__(16) u16 As[128][40];
  __shared__ __align__(16) u16 Bs[128][40];
  const int tid = threadIdx.x;
  const int m0 = blockIdx.y << 7, n0 = blockIdx.x << 7;
  const int lane = tid & 63;
  const int wr = ((tid >> 7) & 1) << 6;
  const int wc = ((tid >> 6) & 1) << 6;
  const int fm = lane & 15;
  const int kl = lane >> 4;
  const int sr = tid >> 1, sc = (tid & 1) << 4;

  f32x4 acc[4][4];
#pragma unroll
  for (int i = 0; i < 4; i++)
#pragma unroll
    for (int j = 0; j < 4; j++) acc[i][j] = (f32x4){0.f, 0.f, 0.f, 0.f};

  const u16* Ab = A + (size_t)(m0 + sr) * K + sc;
  const u16* Wb = Wt + (size_t)woff + (size_t)(n0 + sr) * K + sc;

  for (int k0 = 0; k0 < K; k0 += 32) {
    us8 a0 = *(const us8*)(Ab + k0);
    us8 a1 = *(const us8*)(Ab + k0 + 8);
    us8 w0 = *(const us8*)(Wb + k0);
    us8 w1 = *(const us8*)(Wb + k0 + 8);
    *(us8*)&As[sr][sc]     = a0;
    *(us8*)&As[sr][sc + 8] = a1;
    *(us8*)&Bs[sr][sc]     = w0;
    *(us8*)&Bs[sr][sc + 8] = w1;
    __syncthreads();
    bf16x8 af[4], bfr[4];
#pragma unroll
    for (int i = 0; i < 4; i++)
      af[i] = *reinterpret_cast<const bf16x8*>(&As[wr + i * 16 + fm][kl << 3]);
#pragma unroll
    for (int j = 0; j < 4; j++)
      bfr[j] = *reinterpret_cast<const bf16x8*>(&Bs[wc + j * 16 + fm][kl << 3]);
#pragma unroll
    for (int i = 0; i < 4; i++)
#pragma unroll
      for (int j = 0; j < 4; j++)
        acc[i][j] = __builtin_amdgcn_mfma_f32_16x16x32_bf16(af[i], bfr[j], acc[i][j], 0, 0, 0);
    __syncthreads();
  }

  // D mapping: col = lane&15, row = (lane>>4)*4 + reg
  const int rb = m0 + wr + (kl << 2);
  const int cb = n0 + wc + fm;
  float bv[4];
#pragma unroll
  for (int j = 0; j < 4; j++) bv[j] = ldf(bias, boff + cb + j * 16, f32);
#pragma unroll
  for (int i = 0; i < 4; i++) {
#pragma unroll
    for (int e = 0; e < 4; e++) {
      size_t roff = (size_t)(rb + i * 16 + e) * N;
#pragma unroll
      for (int j = 0; j < 4; j++) {
        float v = acc[i][j][e] + bv[j];
        if (mode == 1) {
          ((float*)C)[roff + cb + j * 16] = v + resid[roff + cb + j * 16];
        } else {
          if (mode == 2) v = v / (1.f + __expf(-v));
          ((u16*)C)[roff + cb + j * 16] = f2bu(v);
        }
      }
    }
  }
}

// ---------------- logits head: C[M,N] = A[M,K] @ tebf[N,K]^T via bf16 MFMA ----------------
// Grid (32 m, 250 n): m fast-varying -> consecutive blocks share one te n-panel (L2/L3 reuse).
__global__ __launch_bounds__(256) void gemm_head_mfma(const u16* __restrict__ A,
    const u16* __restrict__ Wtb, void* __restrict__ C, const void* probe) {
  const int f32 = probe_f32(probe);
  __shared__ __align__(16) u16 As[128][40];
  __shared__ __align__(16) u16 Bs[128][40];
  const int tid = threadIdx.x;
  const int m0 = blockIdx.x << 7, n0 = blockIdx.y << 7;
  const int lane = tid & 63;
  const int wr = ((tid >> 7) & 1) << 6;
  const int wc = ((tid >> 6) & 1) << 6;
  const int fm = lane & 15;
  const int kl = lane >> 4;
  const int sr = tid >> 1, sc = (tid & 1) << 4;

  f32x4 acc[4][4];
#pragma unroll
  for (int i = 0; i < 4; i++)
#pragma unroll
    for (int j = 0; j < 4; j++) acc[i][j] = (f32x4){0.f, 0.f, 0.f, 0.f};

  const u16* Ab = A + (size_t)(m0 + sr) * DMODEL + sc;
  const u16* Wb = Wtb + (size_t)(n0 + sr) * DMODEL + sc;

  for (int k0 = 0; k0 < DMODEL; k0 += 32) {
    us8 a0 = *(const us8*)(Ab + k0);
    us8 a1 = *(const us8*)(Ab + k0 + 8);
    us8 w0 = *(const us8*)(Wb + k0);
    us8 w1 = *(const us8*)(Wb + k0 + 8);
    *(us8*)&As[sr][sc]     = a0;
    *(us8*)&As[sr][sc + 8] = a1;
    *(us8*)&Bs[sr][sc]     = w0;
    *(us8*)&Bs[sr][sc + 8] = w1;
    __syncthreads();
    bf16x8 af[4], bfr[4];
#pragma unroll
    for (int i = 0; i < 4; i++)
      af[i] = *reinterpret_cast<const bf16x8*>(&As[wr + i * 16 + fm][kl << 3]);
#pragma unroll
    for (int j = 0; j < 4; j++)
      bfr[j] = *reinterpret_cast<const bf16x8*>(&Bs[wc + j * 16 + fm][kl << 3]);
#pragma unroll
    for (int i = 0; i < 4; i++)
#pragma unroll
      for (int j = 0; j < 4; j++)
        acc[i][j] = __builtin_amdgcn_mfma_f32_16x16x32_bf16(af[i], bfr[j], acc[i][j], 0, 0, 0);
    __syncthreads();
  }

  const int rbase = m0 + wr + (kl << 2);
  const int cbase = n0 + wc + fm;
#pragma unroll
  for (int i = 0; i < 4; i++) {
#pragma unroll
    for (int j = 0; j < 4; j++) {
#pragma unroll
      for (int e = 0; e < 4; e++) {
        size_t off = (size_t)(rbase + i * 16 + e) * NVOCAB + cbase + j * 16;
        if (f32) ((float*)C)[off] = acc[i][j][e];
        else     ((u16*)C)[off]   = f2bu(acc[i][j][e]);
      }
    }
  }
}

// ---------------- MFMA flash attention (bf16 qkv in, bf16 o out) ----------------
// Block = 4 waves; wave w owns q rows [qt*64 + w*16, +16). Q in registers (A-frags, raw bf16;
// 1/sqrt(64) applied to S post-MFMA in f32). Per kt-tile: K rows -> LDS (us8 copy), V -> LDS
// transposed (u16 scatter, conflict-free). Softmax in-register; P -> LDS bf16 re-read as
// A-frag (same wave only, no barrier).
__global__ __launch_bounds__(256) void attn_mfma(const u16* __restrict__ qkv,
                                                 u16* __restrict__ o) {
  const int qt = blockIdx.x, hh = blockIdx.y, bb = blockIdx.z;
  __shared__ __align__(16) u16 Ks[64][72];   // K[key][d]
  __shared__ __align__(16) u16 Vt[64][72];   // V^T[d][key]
  __shared__ __align__(16) u16 Ps[64][72];   // P[q][key], per-wave 16-row slabs
  const int tid = threadIdx.x;
  const int w = tid >> 6, lane = tid & 63;
  const int fm = lane & 15, kl = lane >> 4;

  // Q fragments: lane holds Q[w*16+fm][c*32 + kl*8 + e], c=0,1 (raw bf16)
  bf16x8 aq[2];
  {
    const u16* qrow = qkv + ((size_t)(bb * TSEQ + qt * 64 + w * 16 + fm)) * 2304 + hh * 64;
#pragma unroll
    for (int c = 0; c < 2; c++) {
      us8 u = *(const us8*)(qrow + c * 32 + kl * 8);
      aq[c] = *(bf16x8*)&u;
    }
  }

  float m_r[4], l_r[4];
#pragma unroll
  for (int e = 0; e < 4; e++) { m_r[e] = -3e38f; l_r[e] = 0.f; }
  f32x4 oacc[4];
#pragma unroll
  for (int j = 0; j < 4; j++) oacc[j] = (f32x4){0.f, 0.f, 0.f, 0.f};

  for (int kt = 0; kt <= qt; kt++) {
    const size_t kbase = ((size_t)(bb * TSEQ + kt * 64)) * 2304 + hh * 64;
    // idx in [0,512): K: row=idx>>3, col-chunk=(idx&7)*8. V: key=idx&63, d-chunk=(idx>>6)*8.
#pragma unroll
    for (int it = 0; it < 2; it++) {
      int idx = tid + it * 256;
      int row = idx >> 3, cb = (idx & 7) << 3;
      *(us8*)&Ks[row][cb] = *(const us8*)(qkv + kbase + (size_t)row * 2304 + 768 + cb);
      int row2 = idx & 63, cb2 = (idx >> 6) << 3;
      us8 vv = *(const us8*)(qkv + kbase + (size_t)row2 * 2304 + 1536 + cb2);
#pragma unroll
      for (int e = 0; e < 8; e++) Vt[cb2 + e][row2] = vv[e];
    }
    __syncthreads();

    // S = Q K^T  (D rows kl*4+e, cols fm+16j)
    f32x4 sacc[4];
#pragma unroll
    for (int j = 0; j < 4; j++) sacc[j] = (f32x4){0.f, 0.f, 0.f, 0.f};
#pragma unroll
    for (int ck = 0; ck < 2; ck++) {
      bf16x8 kb[4];
#pragma unroll
      for (int j = 0; j < 4; j++)
        kb[j] = *reinterpret_cast<const bf16x8*>(&Ks[j * 16 + fm][ck * 32 + (kl << 3)]);
#pragma unroll
      for (int j = 0; j < 4; j++)
        sacc[j] = __builtin_amdgcn_mfma_f32_16x16x32_bf16(aq[ck], kb[j], sacc[j], 0, 0, 0);
    }
    // scale (matches ref: scale after QK^T), then causal mask
#pragma unroll
    for (int j = 0; j < 4; j++)
#pragma unroll
      for (int e = 0; e < 4; e++) sacc[j][e] *= 0.125f;
    if (kt == qt) {
      const int qrow0 = w * 16 + (kl << 2);
#pragma unroll
      for (int j = 0; j < 4; j++)
#pragma unroll
        for (int e = 0; e < 4; e++)
          if (j * 16 + fm > qrow0 + e) sacc[j][e] = -3e38f;
    }
    // online softmax
    float pmax[4];
#pragma unroll
    for (int e = 0; e < 4; e++) {
      pmax[e] = fmaxf(fmaxf(sacc[0][e], sacc[1][e]), fmaxf(sacc[2][e], sacc[3][e]));
    }
#pragma unroll
    for (int msk = 1; msk < 16; msk <<= 1)
#pragma unroll
      for (int e = 0; e < 4; e++) pmax[e] = fmaxf(pmax[e], __shfl_xor(pmax[e], msk));
    float al[4];
#pragma unroll
    for (int e = 0; e < 4; e++) {
      float nm = fmaxf(m_r[e], pmax[e]);
      al[e] = __expf(m_r[e] - nm);
      m_r[e] = nm;
    }
    float psum[4] = {0.f, 0.f, 0.f, 0.f};
#pragma unroll
    for (int j = 0; j < 4; j++)
#pragma unroll
      for (int e = 0; e < 4; e++) {
        float p = __expf(sacc[j][e] - m_r[e]);
        sacc[j][e] = p;
        psum[e] += p;
      }
    // stage P (bf16) for PV A-frag; same-wave rows only -> no barrier needed
#pragma unroll
    for (int j = 0; j < 4; j++)
#pragma unroll
      for (int e = 0; e < 4; e++)
        Ps[w * 16 + (kl << 2) + e][j * 16 + fm] = f2bu(sacc[j][e]);
#pragma unroll
    for (int msk = 1; msk < 16; msk <<= 1)
#pragma unroll
      for (int e = 0; e < 4; e++) psum[e] += __shfl_xor(psum[e], msk);
#pragma unroll
    for (int e = 0; e < 4; e++) l_r[e] = l_r[e] * al[e] + psum[e];
#pragma unroll
    for (int j = 0; j < 4; j++)
#pragma unroll
      for (int e = 0; e < 4; e++) oacc[j][e] *= al[e];
    // O += P V
#pragma unroll
    for (int ck = 0; ck < 2; ck++) {
      bf16x8 pa = *reinterpret_cast<const bf16x8*>(&Ps[w * 16 + fm][ck * 32 + (kl << 3)]);
      bf16x8 vb[4];
#pragma unroll
      for (int j = 0; j < 4; j++)
        vb[j] = *reinterpret_cast<const bf16x8*>(&Vt[j * 16 + fm][ck * 32 + (kl << 3)]);
#pragma unroll
      for (int j = 0; j < 4; j++)
        oacc[j] = __builtin_amdgcn_mfma_f32_16x16x32_bf16(pa, vb[j], oacc[j], 0, 0, 0);
    }
    __syncthreads();
  }

  float linv[4];
#pragma unroll
  for (int e = 0; e < 4; e++) linv[e] = 1.f / l_r[e];
#pragma unroll
  for (int e = 0; e < 4; e++) {
    size_t ob = ((size_t)(bb * TSEQ + qt * 64 + w * 16 + (kl << 2) + e)) * DMODEL + hh * 64 + fm;
#pragma unroll
    for (int j = 0; j < 4; j++) o[ob + j * 16] = f2bu(oacc[j][e] * linv[e]);
  }
}

extern "C" void kernel_launch(void* const* d_in, const int* in_sizes, int n_in,
                              void* d_out, int out_size, void* d_ws, size_t ws_size,
                              hipStream_t stream) {
  const int* ids = (const int*)d_in[0];
  const void* te    = d_in[1];
  const void* pe    = d_in[2];
  const void* ln1_s = d_in[3];
  const void* ln1_b = d_in[4];
  const void* qkv_w = d_in[5];
  const void* qkv_b = d_in[6];
  const void* out_w = d_in[7];
  const void* out_b = d_in[8];
  const void* ln2_s = d_in[9];
  const void* ln2_b = d_in[10];
  const void* up_w  = d_in[11];
  const void* up_b  = d_in[12];
  const void* dn_w  = d_in[13];
  const void* dn_b  = d_in[14];
  const void* lnf_s = d_in[15];
  const void* lnf_b = d_in[16];
  const void* probe = ln1_s;

  // workspace layout (all offsets 16B-aligned):
  float* x  = (float*)d_ws;                          // f32 [4096][768]  residual
  u16* h    = (u16*)(x + (size_t)MROWS * DMODEL);    // bf16 [4096][768] ln out
  u16* ob   = h + (size_t)MROWS * DMODEL;            // bf16 [4096][768] attn out
  u16* qu   = ob + (size_t)MROWS * DMODEL;           // bf16 union: qkv [4096][2304] / ffn [4096][3072]
  u16* wt   = qu + (size_t)MROWS * DFF;
  const size_t qkv_t_sz = (size_t)2304 * 768;
  const size_t out_t_sz = (size_t)768 * 768;
  const size_t up_t_sz  = (size_t)3072 * 768;
  const size_t dn_t_sz  = (size_t)768 * 3072;
  u16* qkv_t = wt;
  u16* out_t = qkv_t + NLAYER * qkv_t_sz;
  u16* up_t  = out_t + NLAYER * out_t_sz;
  u16* dn_t  = up_t  + NLAYER * up_t_sz;
  u16* tebf  = dn_t + NLAYER * dn_t_sz;
  const size_t te_sz = (size_t)NVOCAB * DMODEL;
  // total need ~156 MB; ws_size proven >= 194 MB in prior rounds.

  embed_kernel<<<MROWS, 256, 0, stream>>>(ids, te, pe, x, probe);

  wtrans_kernel<<<dim3(2304/32, 768/64, NLAYER), 256, 0, stream>>>(qkv_w, qkv_t, 768, 2304, probe);
  wtrans_kernel<<<dim3(768/32,  768/64, NLAYER), 256, 0, stream>>>(out_w, out_t, 768, 768, probe);
  wtrans_kernel<<<dim3(3072/32, 768/64, NLAYER), 256, 0, stream>>>(up_w,  up_t,  768, 3072, probe);
  wtrans_kernel<<<dim3(768/32, 3072/64, NLAYER), 256, 0, stream>>>(dn_w,  dn_t,  3072, 768, probe);
  cvt_bf16_kernel<<<(int)((te_sz / 8 + 255) / 256), 256, 0, stream>>>(te, tebf, te_sz, probe);

  for (int l = 0; l < NLAYER; l++) {
    long lD = (long)l * DMODEL;
    ln_kernel<<<MROWS, 256, 0, stream>>>(x, ln1_s, ln1_b, lD, h, probe);
    gemm_mfma<<<dim3(18, 32), 256, 0, stream>>>(h, qkv_t, (long)l * qkv_t_sz,
        qkv_b, (long)l * 2304, nullptr, qu, 2304, DMODEL, 0, probe);
    attn_mfma<<<dim3(32, 12, 2), 256, 0, stream>>>(qu, ob);
    gemm_mfma<<<dim3(6, 32), 256, 0, stream>>>(ob, out_t, (long)l * out_t_sz,
        out_b, lD, x, x, DMODEL, DMODEL, 1, probe);
    ln_kernel<<<MROWS, 256, 0, stream>>>(x, ln2_s, ln2_b, lD, h, probe);
    gemm_mfma<<<dim3(24, 32), 256, 0, stream>>>(h, up_t, (long)l * up_t_sz,
        up_b, (long)l * DFF, nullptr, qu, DFF, DMODEL, 2, probe);
    gemm_mfma<<<dim3(6, 32), 256, 0, stream>>>(qu, dn_t, (long)l * dn_t_sz,
        dn_b, lD, x, x, DMODEL, DFF, 1, probe);
  }
  ln_kernel<<<MROWS, 256, 0, stream>>>(x, lnf_s, lnf_b, 0, h, probe);
  gemm_head_mfma<<<dim3(32, 250), 256, 0, stream>>>(h, tebf, d_out, probe);
}

// Round 6
// 2301.838 us; speedup vs baseline: 4.2656x; 1.0253x over previous
//
#include <hip/hip_runtime.h>

typedef unsigned short u16;

#define TSEQ 2048
#define DMODEL 768
#define DFF 3072
#define NHEAD 12
#define HDIM 64
#define NLAYER 4
#define NVOCAB 32000
#define MROWS 4096   // B*T

typedef __attribute__((ext_vector_type(8))) __bf16 bf16x8;
typedef __attribute__((ext_vector_type(4))) float f32x4;
typedef __attribute__((ext_vector_type(8))) unsigned short us8;

__device__ __forceinline__ float u2f(u16 u) {
  return __uint_as_float(((unsigned int)u) << 16);
}
__device__ __forceinline__ u16 f2bu(float f) {
  unsigned int u = __float_as_uint(f);
  u += 0x7fffu + ((u >> 16) & 1u);   // round-to-nearest-even
  return (u16)(u >> 16);
}
// dtype probe: ln1_s is all-ones. bf16 -> first u16 = 0x3F80; f32 -> 0x0000 (LE low half).
__device__ __forceinline__ int probe_f32(const void* probe) {
  return ((const u16*)probe)[0] == 0 ? 1 : 0;
}
__device__ __forceinline__ float ldf(const void* p, size_t i, int f32) {
  return f32 ? ((const float*)p)[i] : u2f(((const u16*)p)[i]);
}
__device__ __forceinline__ void ld8(const void* p, size_t i, int f32, float* o) {
  if (f32) {
    const float* q = (const float*)p + i;
    float4 a = *(const float4*)q, b = *(const float4*)(q + 4);
    o[0]=a.x; o[1]=a.y; o[2]=a.z; o[3]=a.w; o[4]=b.x; o[5]=b.y; o[6]=b.z; o[7]=b.w;
  } else {
    const u16* q = (const u16*)p + i;
    ushort4 a = *(const ushort4*)q, b = *(const ushort4*)(q + 4);
    o[0]=u2f(a.x); o[1]=u2f(a.y); o[2]=u2f(a.z); o[3]=u2f(a.w);
    o[4]=u2f(b.x); o[5]=u2f(b.y); o[6]=u2f(b.z); o[7]=u2f(b.w);
  }
}
__device__ __forceinline__ us8 pack8(const float* f) {
  us8 r;
#pragma unroll
  for (int i = 0; i < 8; i++) r[i] = f2bu(f[i]);
  return r;
}
// async global->LDS DMA, 16B per lane. lds dest = wave-uniform base + lane*16.
__device__ __forceinline__ void gld16(const u16* g, u16* l) {
  __builtin_amdgcn_global_load_lds(
      (const __attribute__((address_space(1))) void*)g,
      (__attribute__((address_space(3))) void*)l, 16, 0, 0);
}

// ---------------- embedding (f32 residual stream) ----------------
__global__ __launch_bounds__(256) void embed_kernel(const int* __restrict__ ids,
    const void* __restrict__ te, const void* __restrict__ pe, float* __restrict__ x,
    const void* probe) {
  int f32 = probe_f32(probe);
  int m = blockIdx.x;
  int t = m & (TSEQ - 1);
  int id = ids[m];
  float* xr = x + (size_t)m * DMODEL;
  for (int d = threadIdx.x; d < DMODEL; d += 256)
    xr[d] = ldf(te, (size_t)id * DMODEL + d, f32) + ldf(pe, (size_t)t * DMODEL + d, f32);
}

// ---------------- layernorm: f32 in, bf16 out ----------------
__global__ __launch_bounds__(256) void ln_kernel(const float* __restrict__ x,
    const void* __restrict__ s, const void* __restrict__ b, long soff,
    u16* __restrict__ h, const void* probe) {
  int f32 = probe_f32(probe);
  int m = blockIdx.x;
  const float* xr = x + (size_t)m * DMODEL;
  float v[3];
  float lsum = 0.f, lsq = 0.f;
#pragma unroll
  for (int j = 0; j < 3; j++) {
    float t = xr[threadIdx.x + j * 256];
    v[j] = t; lsum += t; lsq += t * t;
  }
#pragma unroll
  for (int off = 32; off > 0; off >>= 1) {
    lsum += __shfl_down(lsum, off);
    lsq  += __shfl_down(lsq, off);
  }
  __shared__ float wsum[4], wsq[4];
  __shared__ float mu_s, rs_s;
  int wid = threadIdx.x >> 6, lane = threadIdx.x & 63;
  if (lane == 0) { wsum[wid] = lsum; wsq[wid] = lsq; }
  __syncthreads();
  if (threadIdx.x == 0) {
    float su = wsum[0] + wsum[1] + wsum[2] + wsum[3];
    float sq = wsq[0] + wsq[1] + wsq[2] + wsq[3];
    float mu = su * (1.f / DMODEL);
    float var = sq * (1.f / DMODEL) - mu * mu;
    mu_s = mu;
    rs_s = rsqrtf(var + 1e-5f);
  }
  __syncthreads();
  float mu = mu_s, rs = rs_s;
  u16* hr = h + (size_t)m * DMODEL;
#pragma unroll
  for (int j = 0; j < 3; j++) {
    int d = threadIdx.x + j * 256;
    hr[d] = f2bu((v[j] - mu) * rs * ldf(s, soff + d, f32) + ldf(b, soff + d, f32));
  }
}

// ---------------- weight transpose: Wt[n][k] (bf16) <- W[k][n] ----------------
__global__ __launch_bounds__(256) void wtrans_kernel(const void* __restrict__ W,
    u16* __restrict__ Wt, int K, int N, const void* probe) {
  const int f32 = probe_f32(probe);
  __shared__ u16 t[64][33];
  const size_t ls = (size_t)K * N;
  const size_t off = (size_t)blockIdx.z * ls;
  const int k0 = blockIdx.y << 6, n0 = blockIdx.x << 5;
  const int tid = threadIdx.x;
  const int tn = tid & 31, tk8 = tid >> 5;
#pragma unroll
  for (int p = 0; p < 8; p++) {
    int k = (p << 3) + tk8;
    t[k][tn] = f2bu(ldf(W, off + (size_t)(k0 + k) * N + n0 + tn, f32));
  }
  __syncthreads();
  const int kp = (tid & 31) << 1, nb = tid >> 5;
#pragma unroll
  for (int p = 0; p < 4; p++) {
    int n = (p << 3) + nb;
    ushort2 v; v.x = t[kp][n]; v.y = t[kp + 1][n];
    *(ushort2*)&Wt[off + (size_t)(n0 + n) * K + k0 + kp] = v;
  }
}

// ---------------- bf16 convert copy (te -> bf16 [N][K], no transpose) ----------------
__global__ __launch_bounds__(256) void cvt_bf16_kernel(const void* __restrict__ src,
    u16* __restrict__ dst, size_t n, const void* probe) {
  const int f32 = probe_f32(probe);
  size_t i = ((size_t)blockIdx.x * 256 + threadIdx.x) * 8;
  if (i >= n) return;
  float v[8];
  ld8(src, i, f32, v);
  *(us8*)&dst[i] = pack8(v);
}

// ---------------- bf16 MFMA GEMM: C[M,N] = A[M,K] @ Wt[N,K]^T + bias ----------------
// A bf16, Wt bf16 [N][K]. mode 0: C bf16 plain; 1: C f32 += resid; 2: C bf16 silu.
// 128x128 tile, 4 waves of 64x64 (4x4 frags of 16x16x32), BK=32.
// Staging via global_load_lds 16B DMA into linear [128][32] LDS (m97 structure):
// wave w stages rows 16w..16w+15 (region 0) and 64+16w.. (region 1); lane ->
// (row = 16w + lane/4, kchunk = lane&3) matches HW's base+lane*16 linear write.
__global__ __launch_bounds__(256) void gemm_mfma(const u16* __restrict__ A,
    const u16* __restrict__ Wt, long woff, const void* __restrict__ bias, long boff,
    const float* resid, void* C, int N, int K, int mode, const void* probe) {
  const int f32 = probe_f32(probe);
  __shared__ __align__(16) u16 As[128 * 32];
  __shared__ __align__(16) u16 Bs[128 * 32];
  const int tid = threadIdx.x;
  const int m0 = blockIdx.y << 7, n0 = blockIdx.x << 7;
  const int lane = tid & 63;
  const int w = tid >> 6;
  const int wr = ((tid >> 7) & 1) << 6;
  const int wc = ((tid >> 6) & 1) << 6;
  const int fm = lane & 15;
  const int kl = lane >> 4;
  const int srow = (w << 4) + (lane >> 2);   // staging row (region 1 adds 64)
  const int skc  = (lane & 3) << 3;          // staging k-chunk (u16 offset)

  f32x4 acc[4][4];
#pragma unroll
  for (int i = 0; i < 4; i++)
#pragma unroll
    for (int j = 0; j < 4; j++) acc[i][j] = (f32x4){0.f, 0.f, 0.f, 0.f};

  const u16* Ab = A + (size_t)(m0 + srow) * K + skc;
  const u16* Wb = Wt + (size_t)woff + (size_t)(n0 + srow) * K + skc;
  const size_t rstep = (size_t)64 * K;
  u16* lA0 = As + (w << 9);
  u16* lA1 = As + ((w + 4) << 9);
  u16* lB0 = Bs + (w << 9);
  u16* lB1 = Bs + ((w + 4) << 9);

  for (int k0 = 0; k0 < K; k0 += 32) {
    gld16(Ab + k0, lA0);
    gld16(Ab + rstep + k0, lA1);
    gld16(Wb + k0, lB0);
    gld16(Wb + rstep + k0, lB1);
    __syncthreads();
    bf16x8 af[4], bfr[4];
#pragma unroll
    for (int i = 0; i < 4; i++)
      af[i] = *reinterpret_cast<const bf16x8*>(&As[((wr + i * 16 + fm) << 5) + (kl << 3)]);
#pragma unroll
    for (int j = 0; j < 4; j++)
      bfr[j] = *reinterpret_cast<const bf16x8*>(&Bs[((wc + j * 16 + fm) << 5) + (kl << 3)]);
#pragma unroll
    for (int i = 0; i < 4; i++)
#pragma unroll
      for (int j = 0; j < 4; j++)
        acc[i][j] = __builtin_amdgcn_mfma_f32_16x16x32_bf16(af[i], bfr[j], acc[i][j], 0, 0, 0);
    __syncthreads();
  }

  // D mapping: col = lane&15, row = (lane>>4)*4 + reg
  const int rb = m0 + wr + (kl << 2);
  const int cb = n0 + wc + fm;
  float bv[4];
#pragma unroll
  for (int j = 0; j < 4; j++) bv[j] = ldf(bias, boff + cb + j * 16, f32);
#pragma unroll
  for (int i = 0; i < 4; i++) {
#pragma unroll
    for (int e = 0; e < 4; e++) {
      size_t roff = (size_t)(rb + i * 16 + e) * N;
#pragma unroll
      for (int j = 0; j < 4; j++) {
        float v = acc[i][j][e] + bv[j];
        if (mode == 1) {
          ((float*)C)[roff + cb + j * 16] = v + resid[roff + cb + j * 16];
        } else {
          if (mode == 2) v = v / (1.f + __expf(-v));
          ((u16*)C)[roff + cb + j * 16] = f2bu(v);
        }
      }
    }
  }
}

// ---------------- logits head: C[M,N] = A[M,K] @ tebf[N,K]^T via bf16 MFMA ----------------
// Grid (32 m, 250 n): m fast-varying -> consecutive blocks share one te n-panel (L2/L3 reuse).
// Same gload_lds staging as gemm_mfma.
__global__ __launch_bounds__(256) void gemm_head_mfma(const u16* __restrict__ A,
    const u16* __restrict__ Wtb, void* __restrict__ C, const void* probe) {
  const int f32 = probe_f32(probe);
  __shared__ __align__(16) u16 As[128 * 32];
  __shared__ __align__(16) u16 Bs[128 * 32];
  const int tid = threadIdx.x;
  const int m0 = blockIdx.x << 7, n0 = blockIdx.y << 7;
  const int lane = tid & 63;
  const int w = tid >> 6;
  const int wr = ((tid >> 7) & 1) << 6;
  const int wc = ((tid >> 6) & 1) << 6;
  const int fm = lane & 15;
  const int kl = lane >> 4;
  const int srow = (w << 4) + (lane >> 2);
  const int skc  = (lane & 3) << 3;

  f32x4 acc[4][4];
#pragma unroll
  for (int i = 0; i < 4; i++)
#pragma unroll
    for (int j = 0; j < 4; j++) acc[i][j] = (f32x4){0.f, 0.f, 0.f, 0.f};

  const u16* Ab = A + (size_t)(m0 + srow) * DMODEL + skc;
  const u16* Wb = Wtb + (size_t)(n0 + srow) * DMODEL + skc;
  const size_t rstep = (size_t)64 * DMODEL;
  u16* lA0 = As + (w << 9);
  u16* lA1 = As + ((w + 4) << 9);
  u16* lB0 = Bs + (w << 9);
  u16* lB1 = Bs + ((w + 4) << 9);

  for (int k0 = 0; k0 < DMODEL; k0 += 32) {
    gld16(Ab + k0, lA0);
    gld16(Ab + rstep + k0, lA1);
    gld16(Wb + k0, lB0);
    gld16(Wb + rstep + k0, lB1);
    __syncthreads();
    bf16x8 af[4], bfr[4];
#pragma unroll
    for (int i = 0; i < 4; i++)
      af[i] = *reinterpret_cast<const bf16x8*>(&As[((wr + i * 16 + fm) << 5) + (kl << 3)]);
#pragma unroll
    for (int j = 0; j < 4; j++)
      bfr[j] = *reinterpret_cast<const bf16x8*>(&Bs[((wc + j * 16 + fm) << 5) + (kl << 3)]);
#pragma unroll
    for (int i = 0; i < 4; i++)
#pragma unroll
      for (int j = 0; j < 4; j++)
        acc[i][j] = __builtin_amdgcn_mfma_f32_16x16x32_bf16(af[i], bfr[j], acc[i][j], 0, 0, 0);
    __syncthreads();
  }

  const int rbase = m0 + wr + (kl << 2);
  const int cbase = n0 + wc + fm;
#pragma unroll
  for (int i = 0; i < 4; i++) {
#pragma unroll
    for (int j = 0; j < 4; j++) {
#pragma unroll
      for (int e = 0; e < 4; e++) {
        size_t off = (size_t)(rbase + i * 16 + e) * NVOCAB + cbase + j * 16;
        if (f32) ((float*)C)[off] = acc[i][j][e];
        else     ((u16*)C)[off]   = f2bu(acc[i][j][e]);
      }
    }
  }
}

// ---------------- MFMA flash attention (bf16 qkv in, bf16 o out) ----------------
__global__ __launch_bounds__(256) void attn_mfma(const u16* __restrict__ qkv,
                                                 u16* __restrict__ o) {
  const int qt = blockIdx.x, hh = blockIdx.y, bb = blockIdx.z;
  __shared__ __align__(16) u16 Ks[64][72];   // K[key][d]
  __shared__ __align__(16) u16 Vt[64][72];   // V^T[d][key]
  __shared__ __align__(16) u16 Ps[64][72];   // P[q][key], per-wave 16-row slabs
  const int tid = threadIdx.x;
  const int w = tid >> 6, lane = tid & 63;
  const int fm = lane & 15, kl = lane >> 4;

  // Q fragments: lane holds Q[w*16+fm][c*32 + kl*8 + e], c=0,1 (raw bf16)
  bf16x8 aq[2];
  {
    const u16* qrow = qkv + ((size_t)(bb * TSEQ + qt * 64 + w * 16 + fm)) * 2304 + hh * 64;
#pragma unroll
    for (int c = 0; c < 2; c++) {
      us8 u = *(const us8*)(qrow + c * 32 + kl * 8);
      aq[c] = *(bf16x8*)&u;
    }
  }

  float m_r[4], l_r[4];
#pragma unroll
  for (int e = 0; e < 4; e++) { m_r[e] = -3e38f; l_r[e] = 0.f; }
  f32x4 oacc[4];
#pragma unroll
  for (int j = 0; j < 4; j++) oacc[j] = (f32x4){0.f, 0.f, 0.f, 0.f};

  for (int kt = 0; kt <= qt; kt++) {
    const size_t kbase = ((size_t)(bb * TSEQ + kt * 64)) * 2304 + hh * 64;
    // idx in [0,512): K: row=idx>>3, col-chunk=(idx&7)*8. V: key=idx&63, d-chunk=(idx>>6)*8.
#pragma unroll
    for (int it = 0; it < 2; it++) {
      int idx = tid + it * 256;
      int row = idx >> 3, cb = (idx & 7) << 3;
      *(us8*)&Ks[row][cb] = *(const us8*)(qkv + kbase + (size_t)row * 2304 + 768 + cb);
      int row2 = idx & 63, cb2 = (idx >> 6) << 3;
      us8 vv = *(const us8*)(qkv + kbase + (size_t)row2 * 2304 + 1536 + cb2);
#pragma unroll
      for (int e = 0; e < 8; e++) Vt[cb2 + e][row2] = vv[e];
    }
    __syncthreads();

    // S = Q K^T  (D rows kl*4+e, cols fm+16j)
    f32x4 sacc[4];
#pragma unroll
    for (int j = 0; j < 4; j++) sacc[j] = (f32x4){0.f, 0.f, 0.f, 0.f};
#pragma unroll
    for (int ck = 0; ck < 2; ck++) {
      bf16x8 kb[4];
#pragma unroll
      for (int j = 0; j < 4; j++)
        kb[j] = *reinterpret_cast<const bf16x8*>(&Ks[j * 16 + fm][ck * 32 + (kl << 3)]);
#pragma unroll
      for (int j = 0; j < 4; j++)
        sacc[j] = __builtin_amdgcn_mfma_f32_16x16x32_bf16(aq[ck], kb[j], sacc[j], 0, 0, 0);
    }
    // scale (matches ref: scale after QK^T), then causal mask
#pragma unroll
    for (int j = 0; j < 4; j++)
#pragma unroll
      for (int e = 0; e < 4; e++) sacc[j][e] *= 0.125f;
    if (kt == qt) {
      const int qrow0 = w * 16 + (kl << 2);
#pragma unroll
      for (int j = 0; j < 4; j++)
#pragma unroll
        for (int e = 0; e < 4; e++)
          if (j * 16 + fm > qrow0 + e) sacc[j][e] = -3e38f;
    }
    // online softmax
    float pmax[4];
#pragma unroll
    for (int e = 0; e < 4; e++) {
      pmax[e] = fmaxf(fmaxf(sacc[0][e], sacc[1][e]), fmaxf(sacc[2][e], sacc[3][e]));
    }
#pragma unroll
    for (int msk = 1; msk < 16; msk <<= 1)
#pragma unroll
      for (int e = 0; e < 4; e++) pmax[e] = fmaxf(pmax[e], __shfl_xor(pmax[e], msk));
    float al[4];
#pragma unroll
    for (int e = 0; e < 4; e++) {
      float nm = fmaxf(m_r[e], pmax[e]);
      al[e] = __expf(m_r[e] - nm);
      m_r[e] = nm;
    }
    float psum[4] = {0.f, 0.f, 0.f, 0.f};
#pragma unroll
    for (int j = 0; j < 4; j++)
#pragma unroll
      for (int e = 0; e < 4; e++) {
        float p = __expf(sacc[j][e] - m_r[e]);
        sacc[j][e] = p;
        psum[e] += p;
      }
    // stage P (bf16) for PV A-frag; same-wave rows only -> no barrier needed
#pragma unroll
    for (int j = 0; j < 4; j++)
#pragma unroll
      for (int e = 0; e < 4; e++)
        Ps[w * 16 + (kl << 2) + e][j * 16 + fm] = f2bu(sacc[j][e]);
#pragma unroll
    for (int msk = 1; msk < 16; msk <<= 1)
#pragma unroll
      for (int e = 0; e < 4; e++) psum[e] += __shfl_xor(psum[e], msk);
#pragma unroll
    for (int e = 0; e < 4; e++) l_r[e] = l_r[e] * al[e] + psum[e];
#pragma unroll
    for (int j = 0; j < 4; j++)
#pragma unroll
      for (int e = 0; e < 4; e++) oacc[j][e] *= al[e];
    // O += P V
#pragma unroll
    for (int ck = 0; ck < 2; ck++) {
      bf16x8 pa = *reinterpret_cast<const bf16x8*>(&Ps[w * 16 + fm][ck * 32 + (kl << 3)]);
      bf16x8 vb[4];
#pragma unroll
      for (int j = 0; j < 4; j++)
        vb[j] = *reinterpret_cast<const bf16x8*>(&Vt[j * 16 + fm][ck * 32 + (kl << 3)]);
#pragma unroll
      for (int j = 0; j < 4; j++)
        oacc[j] = __builtin_amdgcn_mfma_f32_16x16x32_bf16(pa, vb[j], oacc[j], 0, 0, 0);
    }
    __syncthreads();
  }

  float linv[4];
#pragma unroll
  for (int e = 0; e < 4; e++) linv[e] = 1.f / l_r[e];
#pragma unroll
  for (int e = 0; e < 4; e++) {
    size_t ob = ((size_t)(bb * TSEQ + qt * 64 + w * 16 + (kl << 2) + e)) * DMODEL + hh * 64 + fm;
#pragma unroll
    for (int j = 0; j < 4; j++) o[ob + j * 16] = f2bu(oacc[j][e] * linv[e]);
  }
}

extern "C" void kernel_launch(void* const* d_in, const int* in_sizes, int n_in,
                              void* d_out, int out_size, void* d_ws, size_t ws_size,
                              hipStream_t stream) {
  const int* ids = (const int*)d_in[0];
  const void* te    = d_in[1];
  const void* pe    = d_in[2];
  const void* ln1_s = d_in[3];
  const void* ln1_b = d_in[4];
  const void* qkv_w = d_in[5];
  const void* qkv_b = d_in[6];
  const void* out_w = d_in[7];
  const void* out_b = d_in[8];
  const void* ln2_s = d_in[9];
  const void* ln2_b = d_in[10];
  const void* up_w  = d_in[11];
  const void* up_b  = d_in[12];
  const void* dn_w  = d_in[13];
  const void* dn_b  = d_in[14];
  const void* lnf_s = d_in[15];
  const void* lnf_b = d_in[16];
  const void* probe = ln1_s;

  // workspace layout (all offsets 16B-aligned):
  float* x  = (float*)d_ws;                          // f32 [4096][768]  residual
  u16* h    = (u16*)(x + (size_t)MROWS * DMODEL);    // bf16 [4096][768] ln out
  u16* ob   = h + (size_t)MROWS * DMODEL;            // bf16 [4096][768] attn out
  u16* qu   = ob + (size_t)MROWS * DMODEL;           // bf16 union: qkv [4096][2304] / ffn [4096][3072]
  u16* wt   = qu + (size_t)MROWS * DFF;
  const size_t qkv_t_sz = (size_t)2304 * 768;
  const size_t out_t_sz = (size_t)768 * 768;
  const size_t up_t_sz  = (size_t)3072 * 768;
  const size_t dn_t_sz  = (size_t)768 * 3072;
  u16* qkv_t = wt;
  u16* out_t = qkv_t + NLAYER * qkv_t_sz;
  u16* up_t  = out_t + NLAYER * out_t_sz;
  u16* dn_t  = up_t  + NLAYER * up_t_sz;
  u16* tebf  = dn_t + NLAYER * dn_t_sz;
  const size_t te_sz = (size_t)NVOCAB * DMODEL;

  embed_kernel<<<MROWS, 256, 0, stream>>>(ids, te, pe, x, probe);

  wtrans_kernel<<<dim3(2304/32, 768/64, NLAYER), 256, 0, stream>>>(qkv_w, qkv_t, 768, 2304, probe);
  wtrans_kernel<<<dim3(768/32,  768/64, NLAYER), 256, 0, stream>>>(out_w, out_t, 768, 768, probe);
  wtrans_kernel<<<dim3(3072/32, 768/64, NLAYER), 256, 0, stream>>>(up_w,  up_t,  768, 3072, probe);
  wtrans_kernel<<<dim3(768/32, 3072/64, NLAYER), 256, 0, stream>>>(dn_w,  dn_t,  3072, 768, probe);
  cvt_bf16_kernel<<<(int)((te_sz / 8 + 255) / 256), 256, 0, stream>>>(te, tebf, te_sz, probe);

  for (int l = 0; l < NLAYER; l++) {
    long lD = (long)l * DMODEL;
    ln_kernel<<<MROWS, 256, 0, stream>>>(x, ln1_s, ln1_b, lD, h, probe);
    gemm_mfma<<<dim3(18, 32), 256, 0, stream>>>(h, qkv_t, (long)l * qkv_t_sz,
        qkv_b, (long)l * 2304, nullptr, qu, 2304, DMODEL, 0, probe);
    attn_mfma<<<dim3(32, 12, 2), 256, 0, stream>>>(qu, ob);
    gemm_mfma<<<dim3(6, 32), 256, 0, stream>>>(ob, out_t, (long)l * out_t_sz,
        out_b, lD, x, x, DMODEL, DMODEL, 1, probe);
    ln_kernel<<<MROWS, 256, 0, stream>>>(x, ln2_s, ln2_b, lD, h, probe);
    gemm_mfma<<<dim3(24, 32), 256, 0, stream>>>(h, up_t, (long)l * up_t_sz,
        up_b, (long)l * DFF, nullptr, qu, DFF, DMODEL, 2, probe);
    gemm_mfma<<<dim3(6, 32), 256, 0, stream>>>(qu, dn_t, (long)l * dn_t_sz,
        dn_b, lD, x, x, DMODEL, DFF, 1, probe);
  }
  ln_kernel<<<MROWS, 256, 0, stream>>>(x, lnf_s, lnf_b, 0, h, probe);
  gemm_head_mfma<<<dim3(32, 250), 256, 0, stream>>>(h, tebf, d_out, probe);
}